// Round 8
// baseline (16768.149 us; speedup 1.0000x reference)
//
#include <hip/hip_runtime.h>
#include <hip/hip_bf16.h>
#include <cstdint>
#include <cstddef>

// ---------------------------------------------------------------------------
// StackedLayerNormGRU  (B=64, C_IN=256, H=512, T=1024)
//
// Round 8: R6 (register-resident weights, 64 blocks) with ONE structural
// change: barrier B1 removed. LN stat partials are exchanged through
// epoch-stamped 16B slots (single dwordx4 sc0 sc1 store carries data+epoch;
// readers poll until epoch matches). h0/h1 are parity double-buffered so the
// remaining single barrier (B2, R6 mechanics verbatim) provides all ordering.
// ---------------------------------------------------------------------------

#define NBATCH 64
#define HDIM   512
#define THREE_H 1536
#define CINDIM 256
#define T_STEPS 1024
#define EPSLN 1e-5f
#define NBLK 64   // 32 A-blocks (L0) + 32 B-blocks (L1)
#define HSZ (NBATCH*HDIM)

typedef __bf16 bf8v __attribute__((ext_vector_type(8)));
typedef float f4 __attribute__((ext_vector_type(4)));
typedef float f2 __attribute__((ext_vector_type(2)));
typedef unsigned int u32x4 __attribute__((ext_vector_type(4)));

// ---- workspace layout (bytes) ----
static constexpr size_t OFF_BAR    = 0;          // 64 flags x 128B = 8192
static constexpr size_t OFF_STA    = 8192;       // [64][32][4] f32 = 32768
static constexpr size_t OFF_STB1   = 40960;      // [64][32][4] f32 = 32768
static constexpr size_t OFF_STB2   = 73728;      // [64][32][4] f32 = 32768
static constexpr size_t OFF_H0BF   = 106496;     // [2][64][512] bf16 = 131072
static constexpr size_t OFF_H1BF   = 237568;     // [2][64][512] bf16 = 131072
static constexpr size_t OFF_STATSX = 368640;     // [1024][64][2] f32 = 524288
static constexpr size_t OFF_WH0HI  = 892928;     // 1536*512 bf16 = 1572864 each
static constexpr size_t OFF_WH0LO  = OFF_WH0HI + 1572864;
static constexpr size_t OFF_WX1HI  = OFF_WH0LO + 1572864;
static constexpr size_t OFF_WX1LO  = OFF_WX1HI + 1572864;
static constexpr size_t OFF_WH1HI  = OFF_WX1LO + 1572864;
static constexpr size_t OFF_WH1LO  = OFF_WH1HI + 1572864;
static constexpr size_t OFF_WX0HI  = OFF_WH1LO + 1572864;   // 1536*256 bf16
static constexpr size_t OFF_WX0LO  = OFF_WX0HI + 786432;
static constexpr size_t OFF_XST    = OFF_WX0LO + 786432;    // 33554432
static constexpr size_t OFF_GX0    = OFF_XST + 33554432;    // 201326592

__device__ __forceinline__ f4 mf(bf8v a, bf8v b, f4 c){
  return __builtin_amdgcn_mfma_f32_16x16x32_bf16(a, b, c, 0, 0, 0);
}
__device__ __forceinline__ float sigf(float x){ return 1.0f/(1.0f + __expf(-x)); }
__device__ __forceinline__ float tanhfast(float x){ return 1.0f - 2.0f/(__expf(2.0f*x) + 1.0f); }

// ---- device-coherent (MALL) access helpers ----
__device__ __forceinline__ bf8v ld16_cross(const void* p){
  u32x4 t;
  asm volatile("global_load_dwordx4 %0, %1, off sc0 sc1" : "=v"(t) : "v"(p));
  return __builtin_bit_cast(bf8v, t);
}
__device__ __forceinline__ f4 ld16f_cross(const float* p){
  f4 v;
  asm volatile("global_load_dwordx4 %0, %1, off sc0 sc1" : "=v"(v) : "v"(p));
  return v;
}
__device__ __forceinline__ f4 ld16f_poll(const float* p){
  f4 v;
  asm volatile("global_load_dwordx4 %0, %1, off sc0 sc1\n\ts_waitcnt vmcnt(0)"
               : "=v"(v) : "v"(p) : "memory");
  return v;
}
__device__ __forceinline__ void st2_cross(__hip_bfloat16* p, unsigned int u){
  asm volatile("global_store_short %0, %1, off sc0 sc1" :: "v"(p), "v"(u));
}
__device__ __forceinline__ void st16f_cross(float* p, f4 v){
  asm volatile("global_store_dwordx4 %0, %1, off sc0 sc1" :: "v"(p), "v"(v));
}
__device__ __forceinline__ void vm_drain(){
  asm volatile("s_waitcnt vmcnt(0)" ::: "memory");
  __builtin_amdgcn_sched_barrier(0);
}

// ---- distributed flag barrier (R6-proven): 64 flags, 128B apart ----
__device__ __forceinline__ void gbar(unsigned int* flags, unsigned int target){
  asm volatile("s_waitcnt vmcnt(0) lgkmcnt(0)" ::: "memory");
  __syncthreads();
  if (threadIdx.x == 0){
    unsigned int* myf = flags + (size_t)blockIdx.x * 32;
    asm volatile("global_store_dword %0, %1, off sc0 sc1" :: "v"(myf), "v"(target) : "memory");
  }
  const int lane = threadIdx.x & 63;
  const unsigned int* pf = flags + (size_t)lane * 32;
  for (;;){
    unsigned int v;
    asm volatile("global_load_dword %0, %1, off sc0 sc1\n\ts_waitcnt vmcnt(0)"
                 : "=v"(v) : "v"(pf) : "memory");
    if (__all((int)(v >= target))) break;
    __builtin_amdgcn_s_sleep(1);
  }
}

// ---- K0: zero head of workspace ----
__global__ void k_zero(unsigned int* p, int nwords){
  for (int i = blockIdx.x*blockDim.x + threadIdx.x; i < nwords; i += gridDim.x*blockDim.x)
    p[i] = 0u;
}

// ---- K1: fp32 weight -> bf16 hi/lo split ----
__global__ void k_conv(const float* __restrict__ src, __hip_bfloat16* __restrict__ hi,
                       __hip_bfloat16* __restrict__ lo, int n){
  for (int i = blockIdx.x*blockDim.x + threadIdx.x; i < n; i += gridDim.x*blockDim.x){
    float w = src[i];
    __hip_bfloat16 h = __float2bfloat16(w);
    hi[i] = h;
    lo[i] = __float2bfloat16(w - __bfloat162float(h));
  }
}

// ---- K1b: xs [B][C][T] f32 -> xsT [T][B][C] bf16 ----
__global__ void k_tr(const float* __restrict__ xs, __hip_bfloat16* __restrict__ xsT){
  const int total = NBATCH * CINDIM * (T_STEPS/4);
  for (int idx = blockIdx.x*blockDim.x + threadIdx.x; idx < total; idx += gridDim.x*blockDim.x){
    int b  = idx >> 16;
    int c  = (idx >> 8) & 255;
    int t4 = idx & 255;
    const float4 v = *(const float4*)(xs + ((size_t)b*CINDIM + c)*T_STEPS + t4*4);
    float vv[4] = {v.x, v.y, v.z, v.w};
    #pragma unroll
    for (int i = 0; i < 4; ++i)
      xsT[(size_t)(4*t4 + i)*(NBATCH*CINDIM) + b*CINDIM + c] = __float2bfloat16(vv[i]);
  }
}

// ---- K2: gate_x0 raw GEMM + stat atomics (proven code) ----
__global__ __launch_bounds__(256,1) void k_xgemm(unsigned char* __restrict__ ws){
  const int tid = threadIdx.x;
  const int bx = blockIdx.x;
  const int t = bx >> 4, s = bx & 15;
  const int lane = tid & 63, w = tid >> 6, l15 = lane & 15, lg = lane >> 4;

  const __hip_bfloat16* X  = (const __hip_bfloat16*)(ws + OFF_XST) + (size_t)t*(NBATCH*CINDIM);
  const __hip_bfloat16* WH = (const __hip_bfloat16*)(ws + OFF_WX0HI);
  const __hip_bfloat16* WL = (const __hip_bfloat16*)(ws + OFF_WX0LO);
  float* statsX = (float*)(ws + OFF_STATSX);
  __hip_bfloat16* GX0 = (__hip_bfloat16*)(ws + OFF_GX0) + (size_t)t*(NBATCH*THREE_H);

  __shared__ __hip_bfloat16 SB[2][2][96][72];

  f4 acc[6];
  #pragma unroll
  for (int i = 0; i < 6; ++i) acc[i] = f4{0.f,0.f,0.f,0.f};

  bf8v A0[8];
  #pragma unroll
  for (int kk = 0; kk < 8; ++kk)
    A0[kk] = *(const bf8v*)(X + (16*w + l15)*CINDIM + kk*32 + 8*lg);

  bf8v pre[6];
  #pragma unroll
  for (int rep = 0; rep < 6; ++rep){
    int idx = tid + rep*256; int half = idx >= 768 ? 1 : 0; int i2 = idx - half*768;
    int rr = i2 >> 3, ko = (i2 & 7)*8;
    int j = 32*s + (rr & 31) + 512*(rr >> 5);
    const __hip_bfloat16* sp = (half ? WL : WH) + (size_t)j*CINDIM;
    pre[rep] = *(const bf8v*)(sp + ko);
  }
  #pragma unroll
  for (int chk = 0; chk < 4; ++chk){
    #pragma unroll
    for (int rep = 0; rep < 6; ++rep){
      int idx = tid + rep*256; int half = idx >= 768 ? 1 : 0; int i2 = idx - half*768;
      int rr = i2 >> 3, ko = (i2 & 7)*8;
      *(bf8v*)&SB[chk & 1][half][rr][ko] = pre[rep];
    }
    __syncthreads();
    if (chk < 3){
      #pragma unroll
      for (int rep = 0; rep < 6; ++rep){
        int idx = tid + rep*256; int half = idx >= 768 ? 1 : 0; int i2 = idx - half*768;
        int rr = i2 >> 3, ko = (i2 & 7)*8;
        int j = 32*s + (rr & 31) + 512*(rr >> 5);
        const __hip_bfloat16* sp = (half ? WL : WH) + (size_t)j*CINDIM;
        pre[rep] = *(const bf8v*)(sp + (chk+1)*64 + ko);
      }
    }
    #pragma unroll
    for (int sub = 0; sub < 2; ++sub){
      int kk = 2*chk + sub; int ko = 32*sub + 8*lg;
      bf8v a = A0[kk];
      #pragma unroll
      for (int nf = 0; nf < 6; ++nf){
        bf8v bh = *(const bf8v*)&SB[chk & 1][0][16*nf + l15][ko];
        bf8v bl = *(const bf8v*)&SB[chk & 1][1][16*nf + l15][ko];
        acc[nf] = mf(a, bh, acc[nf]);
        acc[nf] = mf(a, bl, acc[nf]);
      }
    }
  }

  #pragma unroll
  for (int r = 0; r < 4; ++r){
    int row = 16*w + 4*lg + r;
    float sm = 0.f, sq = 0.f;
    #pragma unroll
    for (int nf = 0; nf < 6; ++nf){
      float v = acc[nf][r];
      sm += v; sq += v*v;
      int tc = 16*nf + l15;
      int j = 32*s + (tc & 31) + 512*(tc >> 5);
      GX0[(size_t)row*THREE_H + j] = __float2bfloat16(v);
    }
    #pragma unroll
    for (int m = 1; m < 16; m <<= 1){ sm += __shfl_xor(sm, m); sq += __shfl_xor(sq, m); }
    if (l15 == 0){
      atomicAdd(&statsX[((size_t)t*64 + row)*2 + 0], sm);
      atomicAdd(&statsX[((size_t)t*64 + row)*2 + 1], sq);
    }
  }
}

// ---- K2b: finalize x stats ----
__global__ void k_statsx(float* __restrict__ sx){
  int i = blockIdx.x*blockDim.x + threadIdx.x;
  if (i < T_STEPS*NBATCH){
    float s = sx[2*i], q = sx[2*i+1];
    float m = s * (1.0f/1536.0f);
    float v = fmaxf(q * (1.0f/1536.0f) - m*m, 0.0f);
    sx[2*i] = m;
    sx[2*i+1] = rsqrtf(v + EPSLN);
  }
}

// ===========================================================================
// K3 worker paths.
// ===========================================================================

// ---- A-path: layer-0 recurrence, Wh0 strip in registers ----
__device__ __forceinline__ void runA(
    int s, unsigned char* ws, f4* red, f2* BC0,
    const float* gxg, const float* gxb, const float* ghg, const float* ghb)
{
  const int tid = threadIdx.x, lane = tid & 63, w = tid >> 6;
  const int l15 = lane & 15, lg = (lane >> 4) & 3;

  unsigned int* flags = (unsigned int*)(ws + OFF_BAR);
  float* stA = (float*)(ws + OFF_STA);               // [64][32][4] epoch slots
  __hip_bfloat16* h0bf = (__hip_bfloat16*)(ws + OFF_H0BF);  // [2][64][512]
  const float* statsX = (const float*)(ws + OFF_STATSX);
  const __hip_bfloat16* GX0 = (const __hip_bfloat16*)(ws + OFF_GX0);

  bf8v BW[3][4][2];
  {
    const __hip_bfloat16* hi = (const __hip_bfloat16*)(ws + OFF_WH0HI);
    const __hip_bfloat16* lo = (const __hip_bfloat16*)(ws + OFF_WH0LO);
    #pragma unroll
    for (int g = 0; g < 3; ++g){
      const size_t j = (size_t)(16*s + l15 + 512*g);
      #pragma unroll
      for (int kt = 0; kt < 4; ++kt){
        const size_t ko = (size_t)((4*w + kt)*32 + 8*lg);
        BW[g][kt][0] = *(const bf8v*)(hi + j*HDIM + ko);
        BW[g][kt][1] = *(const bf8v*)(lo + j*HDIM + ko);
      }
    }
  }
  float PXg[3], PXb[3], PHg[3], PHb[3];
  #pragma unroll
  for (int g = 0; g < 3; ++g){
    int j = 16*s + l15 + 512*g;
    PXg[g] = gxg[j]; PXb[g] = gxb[j]; PHg[g] = ghg[j]; PHb[g] = ghb[j];
  }

  float hp[4] = {0.f,0.f,0.f,0.f};
  unsigned int bc = 0;

  for (int tau = 0; tau < T_STEPS; ++tau){
    const float ef = (float)(tau + 1);                 // epoch stamp (nonzero)
    const __hip_bfloat16* h0r = h0bf + (size_t)((tau + 1) & 1) * HSZ;  // parity tau-1
    __hip_bfloat16*       h0w = h0bf + (size_t)(tau & 1) * HSZ;

    f4 zx[3];
    float gxraw[3][4], mxv[4], rsxv[4];

    // -------- P1: GEMM + stat slot stores --------
    bf8v AR[4][4];
    #pragma unroll
    for (int rt = 0; rt < 4; ++rt)
      #pragma unroll
      for (int kt = 0; kt < 4; ++kt)
        AR[rt][kt] = ld16_cross(h0r + (size_t)(16*rt + l15)*HDIM + (4*w + kt)*32 + 8*lg);
    vm_drain();

    f4 AC[3][4];
    #pragma unroll
    for (int g = 0; g < 3; ++g)
      #pragma unroll
      for (int rt = 0; rt < 4; ++rt) AC[g][rt] = f4{0.f,0.f,0.f,0.f};
    #pragma unroll
    for (int kt = 0; kt < 4; ++kt)
      #pragma unroll
      for (int g = 0; g < 3; ++g)
        #pragma unroll
        for (int rt = 0; rt < 4; ++rt){
          AC[g][rt] = mf(AR[rt][kt], BW[g][kt][0], AC[g][rt]);
          AC[g][rt] = mf(AR[rt][kt], BW[g][kt][1], AC[g][rt]);
        }

    #pragma unroll
    for (int r = 0; r < 4; ++r){
      int row = 16*w + 4*lg + r;
      mxv[r]  = statsX[((size_t)tau*64 + row)*2 + 0];
      rsxv[r] = statsX[((size_t)tau*64 + row)*2 + 1];
      #pragma unroll
      for (int g = 0; g < 3; ++g)
        gxraw[g][r] = __bfloat162float(
          GX0[(size_t)tau*(NBATCH*THREE_H) + (size_t)row*THREE_H + (16*s + l15 + 512*g)]);
    }

    #pragma unroll
    for (int g = 0; g < 3; ++g)
      #pragma unroll
      for (int rt = 0; rt < 4; ++rt)
        red[((w*3 + g)*4 + rt)*64 + lane] = AC[g][rt];
    __syncthreads();
    #pragma unroll
    for (int g = 0; g < 3; ++g){
      f4 a = red[((0*3 + g)*4 + w)*64 + lane];
      a += red[((1*3 + g)*4 + w)*64 + lane];
      a += red[((2*3 + g)*4 + w)*64 + lane];
      a += red[((3*3 + g)*4 + w)*64 + lane];
      zx[g] = a;
    }

    #pragma unroll
    for (int r = 0; r < 4; ++r){
      float s1 = zx[0][r] + zx[1][r] + zx[2][r];
      float q1 = zx[0][r]*zx[0][r] + zx[1][r]*zx[1][r] + zx[2][r]*zx[2][r];
      #pragma unroll
      for (int m = 1; m < 16; m <<= 1){ s1 += __shfl_xor(s1, m); q1 += __shfl_xor(q1, m); }
      if (l15 == 0){
        int row = 16*w + 4*lg + r;
        st16f_cross(stA + ((size_t)row*32 + s)*4, f4{s1, q1, ef, 0.f});
      }
    }

    // -------- stats epoch-poll + reduce --------
    {
      int row = tid >> 2, q = tid & 3;
      const float* bp = stA + ((size_t)row*32 + q*8)*4;
      f4 v[8];
      for (;;){
        bool ok = true;
        #pragma unroll
        for (int i = 0; i < 8; ++i){
          v[i] = ld16f_poll(bp + i*4);
          ok = ok && (v[i][2] == ef);
        }
        if (__all((int)ok)) break;
        __builtin_amdgcn_s_sleep(1);
      }
      float sm = 0.f, sq = 0.f;
      #pragma unroll
      for (int i = 0; i < 8; ++i){ sm += v[i][0]; sq += v[i][1]; }
      sm += __shfl_xor(sm,1); sq += __shfl_xor(sq,1);
      sm += __shfl_xor(sm,2); sq += __shfl_xor(sq,2);
      if (q == 0){
        float m = sm*(1.0f/1536.0f);
        float vv = fmaxf(sq*(1.0f/1536.0f) - m*m, 0.0f);
        BC0[row] = f2{m, rsqrtf(vv + EPSLN)};
      }
    }
    __syncthreads();

    // -------- P2: combine + publish h0[tau] --------
    #pragma unroll
    for (int r = 0; r < 4; ++r){
      int row = 16*w + 4*lg + r;
      f2 mr = BC0[row];
      float m = mr[0], rs = mr[1];
      float ghr = (zx[0][r]-m)*rs*PHg[0] + PHb[0];
      float ghi = (zx[1][r]-m)*rs*PHg[1] + PHb[1];
      float ghn = (zx[2][r]-m)*rs*PHg[2] + PHb[2];
      float gxr = (gxraw[0][r] - mxv[r])*rsxv[r]*PXg[0] + PXb[0];
      float gxi = (gxraw[1][r] - mxv[r])*rsxv[r]*PXg[1] + PXb[1];
      float gxn = (gxraw[2][r] - mxv[r])*rsxv[r]*PXg[2] + PXb[2];
      float rg = sigf(gxr + ghr);
      float ig = sigf(gxi + ghi);
      float nn = tanhfast(gxn + rg*ghn);
      float hn = nn + ig*(hp[r] - nn);
      hp[r] = hn;
      __hip_bfloat16 hb = __float2bfloat16(hn);
      st2_cross(h0w + (size_t)row*HDIM + 16*s + l15,
                (unsigned int)*reinterpret_cast<unsigned short*>(&hb));
    }

    gbar(flags, ++bc);   // single barrier per step: h published
  }
}

// ---- B-path: layer-1, Wx1+Wh1 strips in regs, sequential GEMMs ----
__device__ __forceinline__ void runB(
    int s, unsigned char* ws, f4* red, f2* BC1, f2* BC2,
    const float* gxg, const float* gxb, const float* ghg, const float* ghb,
    float* out)
{
  const int tid = threadIdx.x, lane = tid & 63, w = tid >> 6;
  const int l15 = lane & 15, lg = (lane >> 4) & 3;

  unsigned int* flags = (unsigned int*)(ws + OFF_BAR);
  float* stB1 = (float*)(ws + OFF_STB1);   // [64][32][4]
  float* stB2 = (float*)(ws + OFF_STB2);   // [64][32][4]
  __hip_bfloat16* h0bf = (__hip_bfloat16*)(ws + OFF_H0BF);
  __hip_bfloat16* h1bf = (__hip_bfloat16*)(ws + OFF_H1BF);

  bf8v BW[6][4][2];
  {
    const __hip_bfloat16* hix = (const __hip_bfloat16*)(ws + OFF_WX1HI);
    const __hip_bfloat16* lox = (const __hip_bfloat16*)(ws + OFF_WX1LO);
    const __hip_bfloat16* hih = (const __hip_bfloat16*)(ws + OFF_WH1HI);
    const __hip_bfloat16* loh = (const __hip_bfloat16*)(ws + OFF_WH1LO);
    #pragma unroll
    for (int g = 0; g < 3; ++g){
      const size_t j = (size_t)(16*s + l15 + 512*g);
      #pragma unroll
      for (int kt = 0; kt < 4; ++kt){
        const size_t ko = (size_t)((4*w + kt)*32 + 8*lg);
        BW[g][kt][0]   = *(const bf8v*)(hix + j*HDIM + ko);
        BW[g][kt][1]   = *(const bf8v*)(lox + j*HDIM + ko);
        BW[3+g][kt][0] = *(const bf8v*)(hih + j*HDIM + ko);
        BW[3+g][kt][1] = *(const bf8v*)(loh + j*HDIM + ko);
      }
    }
  }
  float PXg[3], PXb[3], PHg[3], PHb[3];
  #pragma unroll
  for (int g = 0; g < 3; ++g){
    int j = 16*s + l15 + 512*g;
    PXg[g] = gxg[j]; PXb[g] = gxb[j]; PHg[g] = ghg[j]; PHb[g] = ghb[j];
  }

  float hp[4] = {0.f,0.f,0.f,0.f};
  unsigned int bc = 0;

  for (int tau = 0; tau < T_STEPS; ++tau){
    const bool act = (tau >= 1);
    const float ef = (float)tau;                       // nonzero when act
    const __hip_bfloat16* h0r = h0bf + (size_t)((tau + 1) & 1) * HSZ;  // h0[tau-1]
    const __hip_bfloat16* h1r = h1bf + (size_t)((tau + 1) & 1) * HSZ;  // h1[tau-2]
    __hip_bfloat16*       h1w = h1bf + (size_t)(tau & 1) * HSZ;

    f4 zx[3], zh[3];

    if (act){
      bf8v AR[4][4];
      #pragma unroll
      for (int rt = 0; rt < 4; ++rt)
        #pragma unroll
        for (int kt = 0; kt < 4; ++kt)
          AR[rt][kt] = ld16_cross(h0r + (size_t)(16*rt + l15)*HDIM + (4*w + kt)*32 + 8*lg);
      vm_drain();

      f4 AC[3][4];
      #pragma unroll
      for (int g = 0; g < 3; ++g)
        #pragma unroll
        for (int rt = 0; rt < 4; ++rt) AC[g][rt] = f4{0.f,0.f,0.f,0.f};
      #pragma unroll
      for (int kt = 0; kt < 4; ++kt)
        #pragma unroll
        for (int g = 0; g < 3; ++g)
          #pragma unroll
          for (int rt = 0; rt < 4; ++rt){
            AC[g][rt] = mf(AR[rt][kt], BW[g][kt][0], AC[g][rt]);
            AC[g][rt] = mf(AR[rt][kt], BW[g][kt][1], AC[g][rt]);
          }
      #pragma unroll
      for (int g = 0; g < 3; ++g)
        #pragma unroll
        for (int rt = 0; rt < 4; ++rt)
          red[((w*3 + g)*4 + rt)*64 + lane] = AC[g][rt];

      #pragma unroll
      for (int rt = 0; rt < 4; ++rt)
        #pragma unroll
        for (int kt = 0; kt < 4; ++kt)
          AR[rt][kt] = ld16_cross(h1r + (size_t)(16*rt + l15)*HDIM + (4*w + kt)*32 + 8*lg);

      __syncthreads();
      #pragma unroll
      for (int g = 0; g < 3; ++g){
        f4 a = red[((0*3 + g)*4 + w)*64 + lane];
        a += red[((1*3 + g)*4 + w)*64 + lane];
        a += red[((2*3 + g)*4 + w)*64 + lane];
        a += red[((3*3 + g)*4 + w)*64 + lane];
        zx[g] = a;
      }
      __syncthreads();

      vm_drain();
      #pragma unroll
      for (int g = 0; g < 3; ++g)
        #pragma unroll
        for (int rt = 0; rt < 4; ++rt) AC[g][rt] = f4{0.f,0.f,0.f,0.f};
      #pragma unroll
      for (int kt = 0; kt < 4; ++kt)
        #pragma unroll
        for (int g = 0; g < 3; ++g)
          #pragma unroll
          for (int rt = 0; rt < 4; ++rt){
            AC[g][rt] = mf(AR[rt][kt], BW[3+g][kt][0], AC[g][rt]);
            AC[g][rt] = mf(AR[rt][kt], BW[3+g][kt][1], AC[g][rt]);
          }
      #pragma unroll
      for (int g = 0; g < 3; ++g)
        #pragma unroll
        for (int rt = 0; rt < 4; ++rt)
          red[((w*3 + g)*4 + rt)*64 + lane] = AC[g][rt];
      __syncthreads();
      #pragma unroll
      for (int g = 0; g < 3; ++g){
        f4 a = red[((0*3 + g)*4 + w)*64 + lane];
        a += red[((1*3 + g)*4 + w)*64 + lane];
        a += red[((2*3 + g)*4 + w)*64 + lane];
        a += red[((3*3 + g)*4 + w)*64 + lane];
        zh[g] = a;
      }

      #pragma unroll
      for (int r = 0; r < 4; ++r){
        float s1 = zx[0][r] + zx[1][r] + zx[2][r];
        float q1 = zx[0][r]*zx[0][r] + zx[1][r]*zx[1][r] + zx[2][r]*zx[2][r];
        float s2 = zh[0][r] + zh[1][r] + zh[2][r];
        float q2 = zh[0][r]*zh[0][r] + zh[1][r]*zh[1][r] + zh[2][r]*zh[2][r];
        #pragma unroll
        for (int m = 1; m < 16; m <<= 1){
          s1 += __shfl_xor(s1, m); q1 += __shfl_xor(q1, m);
          s2 += __shfl_xor(s2, m); q2 += __shfl_xor(q2, m);
        }
        if (l15 == 0){
          int row = 16*w + 4*lg + r;
          st16f_cross(stB1 + ((size_t)row*32 + s)*4, f4{s1, q1, ef, 0.f});
          st16f_cross(stB2 + ((size_t)row*32 + s)*4, f4{s2, q2, ef, 0.f});
        }
      }

      // -------- stats epoch-poll + reduce --------
      {
        int row = tid >> 2, q = tid & 3;
        const float* b1 = stB1 + ((size_t)row*32 + q*8)*4;
        const float* b2 = stB2 + ((size_t)row*32 + q*8)*4;
        f4 v1[8], v2[8];
        for (;;){
          bool ok = true;
          #pragma unroll
          for (int i = 0; i < 8; ++i){
            v1[i] = ld16f_poll(b1 + i*4);
            v2[i] = ld16f_poll(b2 + i*4);
            ok = ok && (v1[i][2] == ef) && (v2[i][2] == ef);
          }
          if (__all((int)ok)) break;
          __builtin_amdgcn_s_sleep(1);
        }
        float s1 = 0.f, q1 = 0.f, s2 = 0.f, q2 = 0.f;
        #pragma unroll
        for (int i = 0; i < 8; ++i){
          s1 += v1[i][0]; q1 += v1[i][1];
          s2 += v2[i][0]; q2 += v2[i][1];
        }
        s1 += __shfl_xor(s1,1); q1 += __shfl_xor(q1,1);
        s1 += __shfl_xor(s1,2); q1 += __shfl_xor(q1,2);
        s2 += __shfl_xor(s2,1); q2 += __shfl_xor(q2,1);
        s2 += __shfl_xor(s2,2); q2 += __shfl_xor(q2,2);
        if (q == 0){
          float m1 = s1*(1.0f/1536.0f);
          float vv1 = fmaxf(q1*(1.0f/1536.0f) - m1*m1, 0.0f);
          BC1[row] = f2{m1, rsqrtf(vv1 + EPSLN)};
          float m2 = s2*(1.0f/1536.0f);
          float vv2 = fmaxf(q2*(1.0f/1536.0f) - m2*m2, 0.0f);
          BC2[row] = f2{m2, rsqrtf(vv2 + EPSLN)};
        }
      }
      __syncthreads();

      // -------- P2: combine + publish h1[tau-1] + out --------
      const int t1 = tau - 1;
      #pragma unroll
      for (int r = 0; r < 4; ++r){
        int row = 16*w + 4*lg + r;
        f2 m1 = BC1[row], m2 = BC2[row];
        float gxr = (zx[0][r] - m1[0])*m1[1]*PXg[0] + PXb[0];
        float gxi = (zx[1][r] - m1[0])*m1[1]*PXg[1] + PXb[1];
        float gxn = (zx[2][r] - m1[0])*m1[1]*PXg[2] + PXb[2];
        float ghr = (zh[0][r] - m2[0])*m2[1]*PHg[0] + PHb[0];
        float ghi = (zh[1][r] - m2[0])*m2[1]*PHg[1] + PHb[1];
        float ghn = (zh[2][r] - m2[0])*m2[1]*PHg[2] + PHb[2];
        float rg = sigf(gxr + ghr);
        float ig = sigf(gxi + ghi);
        float nn = tanhfast(gxn + rg*ghn);
        float hn = nn + ig*(hp[r] - nn);
        hp[r] = hn;
        int j = 16*s + l15;
        __hip_bfloat16 hb = __float2bfloat16(hn);
        st2_cross(h1w + (size_t)row*HDIM + j,
                  (unsigned int)*reinterpret_cast<unsigned short*>(&hb));
        out[(size_t)row*(HDIM*T_STEPS) + (size_t)j*T_STEPS + t1] = hn;
      }
    }

    gbar(flags, ++bc);   // single barrier per step
  }

  // ---- epilogue: final step's h1[1023] (z from h0[1023], h1[1022]) ----
  {
    const int tau = T_STEPS;
    const float ef = (float)tau;
    const __hip_bfloat16* h0r = h0bf + (size_t)((tau + 1) & 1) * HSZ;
    const __hip_bfloat16* h1r = h1bf + (size_t)((tau + 1) & 1) * HSZ;

    f4 zx[3], zh[3];
    bf8v AR[4][4];
    #pragma unroll
    for (int rt = 0; rt < 4; ++rt)
      #pragma unroll
      for (int kt = 0; kt < 4; ++kt)
        AR[rt][kt] = ld16_cross(h0r + (size_t)(16*rt + l15)*HDIM + (4*w + kt)*32 + 8*lg);
    vm_drain();
    f4 AC[3][4];
    #pragma unroll
    for (int g = 0; g < 3; ++g)
      #pragma unroll
      for (int rt = 0; rt < 4; ++rt) AC[g][rt] = f4{0.f,0.f,0.f,0.f};
    #pragma unroll
    for (int kt = 0; kt < 4; ++kt)
      #pragma unroll
      for (int g = 0; g < 3; ++g)
        #pragma unroll
        for (int rt = 0; rt < 4; ++rt){
          AC[g][rt] = mf(AR[rt][kt], BW[g][kt][0], AC[g][rt]);
          AC[g][rt] = mf(AR[rt][kt], BW[g][kt][1], AC[g][rt]);
        }
    #pragma unroll
    for (int g = 0; g < 3; ++g)
      #pragma unroll
      for (int rt = 0; rt < 4; ++rt)
        red[((w*3 + g)*4 + rt)*64 + lane] = AC[g][rt];
    #pragma unroll
    for (int rt = 0; rt < 4; ++rt)
      #pragma unroll
      for (int kt = 0; kt < 4; ++kt)
        AR[rt][kt] = ld16_cross(h1r + (size_t)(16*rt + l15)*HDIM + (4*w + kt)*32 + 8*lg);
    __syncthreads();
    #pragma unroll
    for (int g = 0; g < 3; ++g){
      f4 a = red[((0*3 + g)*4 + w)*64 + lane];
      a += red[((1*3 + g)*4 + w)*64 + lane];
      a += red[((2*3 + g)*4 + w)*64 + lane];
      a += red[((3*3 + g)*4 + w)*64 + lane];
      zx[g] = a;
    }
    __syncthreads();
    vm_drain();
    #pragma unroll
    for (int g = 0; g < 3; ++g)
      #pragma unroll
      for (int rt = 0; rt < 4; ++rt) AC[g][rt] = f4{0.f,0.f,0.f,0.f};
    #pragma unroll
    for (int kt = 0; kt < 4; ++kt)
      #pragma unroll
      for (int g = 0; g < 3; ++g)
        #pragma unroll
        for (int rt = 0; rt < 4; ++rt){
          AC[g][rt] = mf(AR[rt][kt], BW[3+g][kt][0], AC[g][rt]);
          AC[g][rt] = mf(AR[rt][kt], BW[3+g][kt][1], AC[g][rt]);
        }
    #pragma unroll
    for (int g = 0; g < 3; ++g)
      #pragma unroll
      for (int rt = 0; rt < 4; ++rt)
        red[((w*3 + g)*4 + rt)*64 + lane] = AC[g][rt];
    __syncthreads();
    #pragma unroll
    for (int g = 0; g < 3; ++g){
      f4 a = red[((0*3 + g)*4 + w)*64 + lane];
      a += red[((1*3 + g)*4 + w)*64 + lane];
      a += red[((2*3 + g)*4 + w)*64 + lane];
      a += red[((3*3 + g)*4 + w)*64 + lane];
      zh[g] = a;
    }
    #pragma unroll
    for (int r = 0; r < 4; ++r){
      float s1 = zx[0][r] + zx[1][r] + zx[2][r];
      float q1 = zx[0][r]*zx[0][r] + zx[1][r]*zx[1][r] + zx[2][r]*zx[2][r];
      float s2 = zh[0][r] + zh[1][r] + zh[2][r];
      float q2 = zh[0][r]*zh[0][r] + zh[1][r]*zh[1][r] + zh[2][r]*zh[2][r];
      #pragma unroll
      for (int m = 1; m < 16; m <<= 1){
        s1 += __shfl_xor(s1, m); q1 += __shfl_xor(q1, m);
        s2 += __shfl_xor(s2, m); q2 += __shfl_xor(q2, m);
      }
      if (l15 == 0){
        int row = 16*w + 4*lg + r;
        st16f_cross(stB1 + ((size_t)row*32 + s)*4, f4{s1, q1, ef, 0.f});
        st16f_cross(stB2 + ((size_t)row*32 + s)*4, f4{s2, q2, ef, 0.f});
      }
    }
    {
      int row = tid >> 2, q = tid & 3;
      const float* b1 = stB1 + ((size_t)row*32 + q*8)*4;
      const float* b2 = stB2 + ((size_t)row*32 + q*8)*4;
      f4 v1[8], v2[8];
      for (;;){
        bool ok = true;
        #pragma unroll
        for (int i = 0; i < 8; ++i){
          v1[i] = ld16f_poll(b1 + i*4);
          v2[i] = ld16f_poll(b2 + i*4);
          ok = ok && (v1[i][2] == ef) && (v2[i][2] == ef);
        }
        if (__all((int)ok)) break;
        __builtin_amdgcn_s_sleep(1);
      }
      float s1 = 0.f, q1 = 0.f, s2 = 0.f, q2 = 0.f;
      #pragma unroll
      for (int i = 0; i < 8; ++i){
        s1 += v1[i][0]; q1 += v1[i][1];
        s2 += v2[i][0]; q2 += v2[i][1];
      }
      s1 += __shfl_xor(s1,1); q1 += __shfl_xor(q1,1);
      s1 += __shfl_xor(s1,2); q1 += __shfl_xor(q1,2);
      s2 += __shfl_xor(s2,1); q2 += __shfl_xor(q2,1);
      s2 += __shfl_xor(s2,2); q2 += __shfl_xor(q2,2);
      if (q == 0){
        float m1 = s1*(1.0f/1536.0f);
        float vv1 = fmaxf(q1*(1.0f/1536.0f) - m1*m1, 0.0f);
        BC1[row] = f2{m1, rsqrtf(vv1 + EPSLN)};
        float m2 = s2*(1.0f/1536.0f);
        float vv2 = fmaxf(q2*(1.0f/1536.0f) - m2*m2, 0.0f);
        BC2[row] = f2{m2, rsqrtf(vv2 + EPSLN)};
      }
    }
    __syncthreads();
    const int t1 = T_STEPS - 1;
    #pragma unroll
    for (int r = 0; r < 4; ++r){
      int row = 16*w + 4*lg + r;
      f2 m1 = BC1[row], m2 = BC2[row];
      float gxr = (zx[0][r] - m1[0])*m1[1]*PXg[0] + PXb[0];
      float gxi = (zx[1][r] - m1[0])*m1[1]*PXg[1] + PXb[1];
      float gxn = (zx[2][r] - m1[0])*m1[1]*PXg[2] + PXb[2];
      float ghr = (zh[0][r] - m2[0])*m2[1]*PHg[0] + PHb[0];
      float ghi = (zh[1][r] - m2[0])*m2[1]*PHg[1] + PHb[1];
      float ghn = (zh[2][r] - m2[0])*m2[1]*PHg[2] + PHb[2];
      float rg = sigf(gxr + ghr);
      float ig = sigf(gxi + ghi);
      float nn = tanhfast(gxn + rg*ghn);
      float hn = nn + ig*(hp[r] - nn);
      int j = 16*s + l15;
      out[(size_t)row*(HDIM*T_STEPS) + (size_t)j*T_STEPS + t1] = hn;
    }
  }
}

// ---- K3: persistent recurrent kernel, 64 blocks x 256 threads ----
__global__ __launch_bounds__(256,1) void k_rnn(
    const float* __restrict__ gx0g, const float* __restrict__ gx0b,
    const float* __restrict__ gh0g, const float* __restrict__ gh0b,
    const float* __restrict__ gx1g, const float* __restrict__ gx1b,
    const float* __restrict__ gh1g, const float* __restrict__ gh1b,
    unsigned char* __restrict__ ws, float* __restrict__ out)
{
  __shared__ f4 red[4*3*4*64];   // 48 KiB
  __shared__ f2 BCa[64];
  __shared__ f2 BCb[64];

  const int bi = blockIdx.x;
  if (bi < 32)
    runA(bi, ws, red, BCa, gx0g, gx0b, gh0g, gh0b);
  else
    runB(bi - 32, ws, red, BCa, BCb, gx1g, gx1b, gh1g, gh1b, out);
}

// ---------------------------------------------------------------------------
extern "C" void kernel_launch(void* const* d_in, const int* in_sizes, int n_in,
                              void* d_out, int out_size, void* d_ws, size_t ws_size,
                              hipStream_t stream) {
  const float* xs  = (const float*)d_in[0];
  const float* Wx0 = (const float*)d_in[1];
  const float* Wh0 = (const float*)d_in[2];
  const float* gx0g = (const float*)d_in[3];
  const float* gx0b = (const float*)d_in[4];
  const float* gh0g = (const float*)d_in[5];
  const float* gh0b = (const float*)d_in[6];
  const float* Wx1 = (const float*)d_in[7];
  const float* Wh1 = (const float*)d_in[8];
  const float* gx1g = (const float*)d_in[9];
  const float* gx1b = (const float*)d_in[10];
  const float* gh1g = (const float*)d_in[11];
  const float* gh1b = (const float*)d_in[12];

  unsigned char* ws = (unsigned char*)d_ws;
  float* out = (float*)d_out;
  (void)in_sizes; (void)n_in; (void)out_size; (void)ws_size;

  // zero flags + stat slots + h parity buffers + statsX (head region)
  k_zero<<<256, 256, 0, stream>>>((unsigned int*)ws, (int)(OFF_WH0HI/4));

  // weight hi/lo conversion
  k_conv<<<512, 256, 0, stream>>>(Wh0, (__hip_bfloat16*)(ws+OFF_WH0HI), (__hip_bfloat16*)(ws+OFF_WH0LO), THREE_H*HDIM);
  k_conv<<<512, 256, 0, stream>>>(Wx1, (__hip_bfloat16*)(ws+OFF_WX1HI), (__hip_bfloat16*)(ws+OFF_WX1LO), THREE_H*HDIM);
  k_conv<<<512, 256, 0, stream>>>(Wh1, (__hip_bfloat16*)(ws+OFF_WH1HI), (__hip_bfloat16*)(ws+OFF_WH1LO), THREE_H*HDIM);
  k_conv<<<512, 256, 0, stream>>>(Wx0, (__hip_bfloat16*)(ws+OFF_WX0HI), (__hip_bfloat16*)(ws+OFF_WX0LO), THREE_H*CINDIM);

  // xs transpose -> xsT bf16
  k_tr<<<4096, 256, 0, stream>>>(xs, (__hip_bfloat16*)(ws+OFF_XST));

  // x-path GEMM for all timesteps
  k_xgemm<<<16384, 256, 0, stream>>>(ws);
  k_statsx<<<256, 256, 0, stream>>>((float*)(ws+OFF_STATSX));

  // persistent recurrence
  k_rnn<<<NBLK, 256, 0, stream>>>(gx0g, gx0b, gh0g, gh0b, gx1g, gx1b, gh1g, gh1b, ws, out);
}

// Round 10
// 16615.034 us; speedup vs baseline: 1.0092x; 1.0092x over previous
//
#include <hip/hip_runtime.h>
#include <hip/hip_bf16.h>
#include <cstdint>
#include <cstddef>

// ---------------------------------------------------------------------------
// StackedLayerNormGRU  (B=64, C_IN=256, H=512, T=1024)
//
// Round 10: barrier-free producer/consumer pipeline.
//  - 64 blocks: 32 "A" (layer-0, Wh0 in regs) + 32 "B" (layer-1, Wx1+Wh1).
//  - No global barriers. Per step, ONE combined flag poll per block
//    (lanes 0-31: flagA lines, lanes 32-63: flagB lines).
//  - h0 4-deep / h1 2-deep rotating buffers; epoch-stamped LN-stat slots
//    (16B dwordx4 carries {sum,sumsq,epoch}); batched poll loads.
//  - A may run up to 3 steps ahead of B -> layers pipeline.
// ---------------------------------------------------------------------------

#define NBATCH 64
#define HDIM   512
#define THREE_H 1536
#define CINDIM 256
#define T_STEPS 1024
#define EPSLN 1e-5f
#define NBLK 64
#define HSZ (NBATCH*HDIM)

typedef __bf16 bf8v __attribute__((ext_vector_type(8)));
typedef float f4 __attribute__((ext_vector_type(4)));
typedef float f2 __attribute__((ext_vector_type(2)));
typedef unsigned int u32x4 __attribute__((ext_vector_type(4)));

// ---- workspace layout (bytes) ----
static constexpr size_t OFF_BAR    = 0;          // 64 flag lines x 128B (A:0-31, B:32-63)
static constexpr size_t OFF_STA    = 8192;       // [64][32][4] f32 epoch slots
static constexpr size_t OFF_STB1   = 40960;      // [64][32][4]
static constexpr size_t OFF_STB2   = 73728;      // [64][32][4]
static constexpr size_t OFF_H0BF   = 106496;     // [4][64][512] bf16 = 262144
static constexpr size_t OFF_H1BF   = 368640;     // [2][64][512] bf16 = 131072
static constexpr size_t OFF_STATSX = 499712;     // [1024][64][2] f32 = 524288
static constexpr size_t OFF_WH0HI  = 1024000;    // 1536*512 bf16 = 1572864 each
static constexpr size_t OFF_WH0LO  = OFF_WH0HI + 1572864;
static constexpr size_t OFF_WX1HI  = OFF_WH0LO + 1572864;
static constexpr size_t OFF_WX1LO  = OFF_WX1HI + 1572864;
static constexpr size_t OFF_WH1HI  = OFF_WX1LO + 1572864;
static constexpr size_t OFF_WH1LO  = OFF_WH1HI + 1572864;
static constexpr size_t OFF_WX0HI  = OFF_WH1LO + 1572864;   // 1536*256 bf16
static constexpr size_t OFF_WX0LO  = OFF_WX0HI + 786432;
static constexpr size_t OFF_XST    = OFF_WX0LO + 786432;    // 33554432
static constexpr size_t OFF_GX0    = OFF_XST + 33554432;    // 201326592

__device__ __forceinline__ f4 mf(bf8v a, bf8v b, f4 c){
  return __builtin_amdgcn_mfma_f32_16x16x32_bf16(a, b, c, 0, 0, 0);
}
__device__ __forceinline__ float sigf(float x){ return 1.0f/(1.0f + __expf(-x)); }
__device__ __forceinline__ float tanhfast(float x){ return 1.0f - 2.0f/(__expf(2.0f*x) + 1.0f); }

// ---- device-coherent (MALL) access helpers ----
__device__ __forceinline__ bf8v ld16_cross(const void* p){
  u32x4 t;
  asm volatile("global_load_dwordx4 %0, %1, off sc0 sc1" : "=v"(t) : "v"(p));
  return __builtin_bit_cast(bf8v, t);
}
__device__ __forceinline__ f4 ld16f_cross(const float* p){
  f4 v;
  asm volatile("global_load_dwordx4 %0, %1, off sc0 sc1" : "=v"(v) : "v"(p));
  return v;
}
__device__ __forceinline__ void st2_cross(__hip_bfloat16* p, unsigned int u){
  asm volatile("global_store_short %0, %1, off sc0 sc1" :: "v"(p), "v"(u));
}
__device__ __forceinline__ void st16f_cross(float* p, f4 v){
  asm volatile("global_store_dwordx4 %0, %1, off sc0 sc1" :: "v"(p), "v"(v));
}
__device__ __forceinline__ void vm_drain(){
  asm volatile("s_waitcnt vmcnt(0)" ::: "memory");
  __builtin_amdgcn_sched_barrier(0);
}

// ---- combined flag poll: lanes 0-31 check flagA lines >= tA,
//      lanes 32-63 check flagB lines >= tB. One wave-load per iteration. ----
__device__ __forceinline__ void dualpoll(const unsigned int* flags, unsigned tA, unsigned tB){
  const int lane = threadIdx.x & 63;
  const unsigned int* pf = flags + (size_t)lane * 32;
  const unsigned tgt = (lane < 32) ? tA : tB;
  for (;;){
    unsigned int v;
    asm volatile("global_load_dword %0, %1, off sc0 sc1\n\ts_waitcnt vmcnt(0)"
                 : "=v"(v) : "v"(pf) : "memory");
    if (__all((int)(v >= tgt))) break;
    __builtin_amdgcn_s_sleep(1);
  }
}

// publish own flag line (call AFTER vm_drain + __syncthreads, tid 0 only)
__device__ __forceinline__ void pubflag(unsigned int* flags, int line, unsigned val){
  unsigned int* p = flags + (size_t)line * 32;
  asm volatile("global_store_dword %0, %1, off sc0 sc1" :: "v"(p), "v"(val) : "memory");
}

// ---- K0: zero head of workspace ----
__global__ void k_zero(unsigned int* p, int nwords){
  for (int i = blockIdx.x*blockDim.x + threadIdx.x; i < nwords; i += gridDim.x*blockDim.x)
    p[i] = 0u;
}

// ---- K1: fp32 weight -> bf16 hi/lo split ----
__global__ void k_conv(const float* __restrict__ src, __hip_bfloat16* __restrict__ hi,
                       __hip_bfloat16* __restrict__ lo, int n){
  for (int i = blockIdx.x*blockDim.x + threadIdx.x; i < n; i += gridDim.x*blockDim.x){
    float w = src[i];
    __hip_bfloat16 h = __float2bfloat16(w);
    hi[i] = h;
    lo[i] = __float2bfloat16(w - __bfloat162float(h));
  }
}

// ---- K1b: xs [B][C][T] f32 -> xsT [T][B][C] bf16 ----
__global__ void k_tr(const float* __restrict__ xs, __hip_bfloat16* __restrict__ xsT){
  const int total = NBATCH * CINDIM * (T_STEPS/4);
  for (int idx = blockIdx.x*blockDim.x + threadIdx.x; idx < total; idx += gridDim.x*blockDim.x){
    int b  = idx >> 16;
    int c  = (idx >> 8) & 255;
    int t4 = idx & 255;
    const float4 v = *(const float4*)(xs + ((size_t)b*CINDIM + c)*T_STEPS + t4*4);
    float vv[4] = {v.x, v.y, v.z, v.w};
    #pragma unroll
    for (int i = 0; i < 4; ++i)
      xsT[(size_t)(4*t4 + i)*(NBATCH*CINDIM) + b*CINDIM + c] = __float2bfloat16(vv[i]);
  }
}

// ---- K2: gate_x0 raw GEMM + stat atomics (proven code) ----
__global__ __launch_bounds__(256,1) void k_xgemm(unsigned char* __restrict__ ws){
  const int tid = threadIdx.x;
  const int bx = blockIdx.x;
  const int t = bx >> 4, s = bx & 15;
  const int lane = tid & 63, w = tid >> 6, l15 = lane & 15, lg = lane >> 4;

  const __hip_bfloat16* X  = (const __hip_bfloat16*)(ws + OFF_XST) + (size_t)t*(NBATCH*CINDIM);
  const __hip_bfloat16* WH = (const __hip_bfloat16*)(ws + OFF_WX0HI);
  const __hip_bfloat16* WL = (const __hip_bfloat16*)(ws + OFF_WX0LO);
  float* statsX = (float*)(ws + OFF_STATSX);
  __hip_bfloat16* GX0 = (__hip_bfloat16*)(ws + OFF_GX0) + (size_t)t*(NBATCH*THREE_H);

  __shared__ __hip_bfloat16 SB[2][2][96][72];

  f4 acc[6];
  #pragma unroll
  for (int i = 0; i < 6; ++i) acc[i] = f4{0.f,0.f,0.f,0.f};

  bf8v A0[8];
  #pragma unroll
  for (int kk = 0; kk < 8; ++kk)
    A0[kk] = *(const bf8v*)(X + (16*w + l15)*CINDIM + kk*32 + 8*lg);

  bf8v pre[6];
  #pragma unroll
  for (int rep = 0; rep < 6; ++rep){
    int idx = tid + rep*256; int half = idx >= 768 ? 1 : 0; int i2 = idx - half*768;
    int rr = i2 >> 3, ko = (i2 & 7)*8;
    int j = 32*s + (rr & 31) + 512*(rr >> 5);
    const __hip_bfloat16* sp = (half ? WL : WH) + (size_t)j*CINDIM;
    pre[rep] = *(const bf8v*)(sp + ko);
  }
  #pragma unroll
  for (int chk = 0; chk < 4; ++chk){
    #pragma unroll
    for (int rep = 0; rep < 6; ++rep){
      int idx = tid + rep*256; int half = idx >= 768 ? 1 : 0; int i2 = idx - half*768;
      int rr = i2 >> 3, ko = (i2 & 7)*8;
      *(bf8v*)&SB[chk & 1][half][rr][ko] = pre[rep];
    }
    __syncthreads();
    if (chk < 3){
      #pragma unroll
      for (int rep = 0; rep < 6; ++rep){
        int idx = tid + rep*256; int half = idx >= 768 ? 1 : 0; int i2 = idx - half*768;
        int rr = i2 >> 3, ko = (i2 & 7)*8;
        int j = 32*s + (rr & 31) + 512*(rr >> 5);
        const __hip_bfloat16* sp = (half ? WL : WH) + (size_t)j*CINDIM;
        pre[rep] = *(const bf8v*)(sp + (chk+1)*64 + ko);
      }
    }
    #pragma unroll
    for (int sub = 0; sub < 2; ++sub){
      int kk = 2*chk + sub; int ko = 32*sub + 8*lg;
      bf8v a = A0[kk];
      #pragma unroll
      for (int nf = 0; nf < 6; ++nf){
        bf8v bh = *(const bf8v*)&SB[chk & 1][0][16*nf + l15][ko];
        bf8v bl = *(const bf8v*)&SB[chk & 1][1][16*nf + l15][ko];
        acc[nf] = mf(a, bh, acc[nf]);
        acc[nf] = mf(a, bl, acc[nf]);
      }
    }
  }

  #pragma unroll
  for (int r = 0; r < 4; ++r){
    int row = 16*w + 4*lg + r;
    float sm = 0.f, sq = 0.f;
    #pragma unroll
    for (int nf = 0; nf < 6; ++nf){
      float v = acc[nf][r];
      sm += v; sq += v*v;
      int tc = 16*nf + l15;
      int j = 32*s + (tc & 31) + 512*(tc >> 5);
      GX0[(size_t)row*THREE_H + j] = __float2bfloat16(v);
    }
    #pragma unroll
    for (int m = 1; m < 16; m <<= 1){ sm += __shfl_xor(sm, m); sq += __shfl_xor(sq, m); }
    if (l15 == 0){
      atomicAdd(&statsX[((size_t)t*64 + row)*2 + 0], sm);
      atomicAdd(&statsX[((size_t)t*64 + row)*2 + 1], sq);
    }
  }
}

// ---- K2b: finalize x stats ----
__global__ void k_statsx(float* __restrict__ sx){
  int i = blockIdx.x*blockDim.x + threadIdx.x;
  if (i < T_STEPS*NBATCH){
    float s = sx[2*i], q = sx[2*i+1];
    float m = s * (1.0f/1536.0f);
    float v = fmaxf(q * (1.0f/1536.0f) - m*m, 0.0f);
    sx[2*i] = m;
    sx[2*i+1] = rsqrtf(v + EPSLN);
  }
}

// ===========================================================================
// K3 worker paths.
// ===========================================================================

// ---- A-path: layer-0 recurrence, Wh0 strip in registers ----
__device__ __forceinline__ void runA(
    int s, unsigned char* ws, f4* red, f2* BC0,
    const float* gxg, const float* gxb, const float* ghg, const float* ghb)
{
  const int tid = threadIdx.x, lane = tid & 63, w = tid >> 6;
  const int l15 = lane & 15, lg = (lane >> 4) & 3;

  unsigned int* flags = (unsigned int*)(ws + OFF_BAR);
  float* stA = (float*)(ws + OFF_STA);                       // [64][32][4] epoch slots
  __hip_bfloat16* h0bf = (__hip_bfloat16*)(ws + OFF_H0BF);   // [4][64][512]
  const float* statsX = (const float*)(ws + OFF_STATSX);
  const __hip_bfloat16* GX0 = (const __hip_bfloat16*)(ws + OFF_GX0);

  bf8v BW[3][4][2];
  {
    const __hip_bfloat16* hi = (const __hip_bfloat16*)(ws + OFF_WH0HI);
    const __hip_bfloat16* lo = (const __hip_bfloat16*)(ws + OFF_WH0LO);
    #pragma unroll
    for (int g = 0; g < 3; ++g){
      const size_t j = (size_t)(16*s + l15 + 512*g);
      #pragma unroll
      for (int kt = 0; kt < 4; ++kt){
        const size_t ko = (size_t)((4*w + kt)*32 + 8*lg);
        BW[g][kt][0] = *(const bf8v*)(hi + j*HDIM + ko);
        BW[g][kt][1] = *(const bf8v*)(lo + j*HDIM + ko);
      }
    }
  }
  float PXg[3], PXb[3], PHg[3], PHb[3];
  #pragma unroll
  for (int g = 0; g < 3; ++g){
    int j = 16*s + l15 + 512*g;
    PXg[g] = gxg[j]; PXb[g] = gxb[j]; PHg[g] = ghg[j]; PHb[g] = ghb[j];
  }

  float hp[4] = {0.f,0.f,0.f,0.f};

  for (int t = 0; t < T_STEPS; ++t){
    const float ef = (float)(t + 1);
    const unsigned tB = (t >= 3) ? (unsigned)(t - 3) : 0u;

    // one combined poll: flagA >= t (h0[t-1] visible), flagB >= t-3 (WAR guard)
    dualpoll(flags, (unsigned)t, tB);

    const __hip_bfloat16* h0r = h0bf + (size_t)((t + 3) & 3) * HSZ;  // h0[t-1]
    __hip_bfloat16*       h0w = h0bf + (size_t)(t & 3) * HSZ;        // h0[t]

    bf8v AR[4][4];
    #pragma unroll
    for (int rt = 0; rt < 4; ++rt)
      #pragma unroll
      for (int kt = 0; kt < 4; ++kt)
        AR[rt][kt] = ld16_cross(h0r + (size_t)(16*rt + l15)*HDIM + (4*w + kt)*32 + 8*lg);
    vm_drain();

    f4 AC[3][4];
    #pragma unroll
    for (int g = 0; g < 3; ++g)
      #pragma unroll
      for (int rt = 0; rt < 4; ++rt) AC[g][rt] = f4{0.f,0.f,0.f,0.f};
    #pragma unroll
    for (int kt = 0; kt < 4; ++kt)
      #pragma unroll
      for (int g = 0; g < 3; ++g)
        #pragma unroll
        for (int rt = 0; rt < 4; ++rt){
          AC[g][rt] = mf(AR[rt][kt], BW[g][kt][0], AC[g][rt]);
          AC[g][rt] = mf(AR[rt][kt], BW[g][kt][1], AC[g][rt]);
        }

    float gxraw[3][4], mxv[4], rsxv[4];
    #pragma unroll
    for (int r = 0; r < 4; ++r){
      int row = 16*w + 4*lg + r;
      mxv[r]  = statsX[((size_t)t*64 + row)*2 + 0];
      rsxv[r] = statsX[((size_t)t*64 + row)*2 + 1];
      #pragma unroll
      for (int g = 0; g < 3; ++g)
        gxraw[g][r] = __bfloat162float(
          GX0[(size_t)t*(NBATCH*THREE_H) + (size_t)row*THREE_H + (16*s + l15 + 512*g)]);
    }

    // K-reduce via LDS
    f4 zx[3];
    #pragma unroll
    for (int g = 0; g < 3; ++g)
      #pragma unroll
      for (int rt = 0; rt < 4; ++rt)
        red[((w*3 + g)*4 + rt)*64 + lane] = AC[g][rt];
    __syncthreads();
    #pragma unroll
    for (int g = 0; g < 3; ++g){
      f4 a = red[((0*3 + g)*4 + w)*64 + lane];
      a += red[((1*3 + g)*4 + w)*64 + lane];
      a += red[((2*3 + g)*4 + w)*64 + lane];
      a += red[((3*3 + g)*4 + w)*64 + lane];
      zx[g] = a;
    }

    // stat partials -> epoch slots
    #pragma unroll
    for (int r = 0; r < 4; ++r){
      float s1 = zx[0][r] + zx[1][r] + zx[2][r];
      float q1 = zx[0][r]*zx[0][r] + zx[1][r]*zx[1][r] + zx[2][r]*zx[2][r];
      #pragma unroll
      for (int m = 1; m < 16; m <<= 1){ s1 += __shfl_xor(s1, m); q1 += __shfl_xor(q1, m); }
      if (l15 == 0){
        int row = 16*w + 4*lg + r;
        st16f_cross(stA + ((size_t)row*32 + s)*4, f4{s1, q1, ef, 0.f});
      }
    }

    // batched epoch poll + reduce
    {
      int row = tid >> 2, q = tid & 3;
      const float* bp = stA + ((size_t)row*32 + q*8)*4;
      f4 v[8];
      for (;;){
        #pragma unroll
        for (int i = 0; i < 8; ++i) v[i] = ld16f_cross(bp + i*4);
        vm_drain();
        bool ok = true;
        #pragma unroll
        for (int i = 0; i < 8; ++i) ok = ok && (v[i][2] >= ef);
        if (__all((int)ok)) break;
        __builtin_amdgcn_s_sleep(1);
      }
      float sm = 0.f, sq = 0.f;
      #pragma unroll
      for (int i = 0; i < 8; ++i){ sm += v[i][0]; sq += v[i][1]; }
      sm += __shfl_xor(sm,1); sq += __shfl_xor(sq,1);
      sm += __shfl_xor(sm,2); sq += __shfl_xor(sq,2);
      if (q == 0){
        float m = sm*(1.0f/1536.0f);
        float vv = fmaxf(sq*(1.0f/1536.0f) - m*m, 0.0f);
        BC0[row] = f2{m, rsqrtf(vv + EPSLN)};
      }
    }
    __syncthreads();

    // combine + publish h0[t]
    #pragma unroll
    for (int r = 0; r < 4; ++r){
      int row = 16*w + 4*lg + r;
      f2 mr = BC0[row];
      float m = mr[0], rs = mr[1];
      float ghr = (zx[0][r]-m)*rs*PHg[0] + PHb[0];
      float ghi = (zx[1][r]-m)*rs*PHg[1] + PHb[1];
      float ghn = (zx[2][r]-m)*rs*PHg[2] + PHb[2];
      float gxr = (gxraw[0][r] - mxv[r])*rsxv[r]*PXg[0] + PXb[0];
      float gxi = (gxraw[1][r] - mxv[r])*rsxv[r]*PXg[1] + PXb[1];
      float gxn = (gxraw[2][r] - mxv[r])*rsxv[r]*PXg[2] + PXb[2];
      float rg = sigf(gxr + ghr);
      float ig = sigf(gxi + ghi);
      float nn = tanhfast(gxn + rg*ghn);
      float hn = nn + ig*(hp[r] - nn);
      hp[r] = hn;
      __hip_bfloat16 hb = __float2bfloat16(hn);
      st2_cross(h0w + (size_t)row*HDIM + 16*s + l15,
                (unsigned int)*reinterpret_cast<unsigned short*>(&hb));
    }

    vm_drain();
    __syncthreads();                 // all threads' h0 stores drained
    if (tid == 0) pubflag(flags, s, (unsigned)(t + 1));
  }
}

// ---- B-path: layer-1, Wx1+Wh1 strips in regs, sequential GEMMs ----
__device__ __forceinline__ void runB(
    int s, unsigned char* ws, f4* red, f2* BC1, f2* BC2,
    const float* gxg, const float* gxb, const float* ghg, const float* ghb,
    float* out)
{
  const int tid = threadIdx.x, lane = tid & 63, w = tid >> 6;
  const int l15 = lane & 15, lg = (lane >> 4) & 3;

  unsigned int* flags = (unsigned int*)(ws + OFF_BAR);
  float* stB1 = (float*)(ws + OFF_STB1);
  float* stB2 = (float*)(ws + OFF_STB2);
  __hip_bfloat16* h0bf = (__hip_bfloat16*)(ws + OFF_H0BF);   // [4][64][512]
  __hip_bfloat16* h1bf = (__hip_bfloat16*)(ws + OFF_H1BF);   // [2][64][512]

  bf8v BW[6][4][2];
  {
    const __hip_bfloat16* hix = (const __hip_bfloat16*)(ws + OFF_WX1HI);
    const __hip_bfloat16* lox = (const __hip_bfloat16*)(ws + OFF_WX1LO);
    const __hip_bfloat16* hih = (const __hip_bfloat16*)(ws + OFF_WH1HI);
    const __hip_bfloat16* loh = (const __hip_bfloat16*)(ws + OFF_WH1LO);
    #pragma unroll
    for (int g = 0; g < 3; ++g){
      const size_t j = (size_t)(16*s + l15 + 512*g);
      #pragma unroll
      for (int kt = 0; kt < 4; ++kt){
        const size_t ko = (size_t)((4*w + kt)*32 + 8*lg);
        BW[g][kt][0]   = *(const bf8v*)(hix + j*HDIM + ko);
        BW[g][kt][1]   = *(const bf8v*)(lox + j*HDIM + ko);
        BW[3+g][kt][0] = *(const bf8v*)(hih + j*HDIM + ko);
        BW[3+g][kt][1] = *(const bf8v*)(loh + j*HDIM + ko);
      }
    }
  }
  float PXg[3], PXb[3], PHg[3], PHb[3];
  #pragma unroll
  for (int g = 0; g < 3; ++g){
    int j = 16*s + l15 + 512*g;
    PXg[g] = gxg[j]; PXb[g] = gxb[j]; PHg[g] = ghg[j]; PHb[g] = ghb[j];
  }

  float hp[4] = {0.f,0.f,0.f,0.f};

  for (int tau = 1; tau <= T_STEPS; ++tau){
    const float ef = (float)tau;

    // one combined poll: flagA >= tau (h0[tau-1]), flagB >= tau-1 (group lockstep + WAR)
    dualpoll(flags, (unsigned)tau, (unsigned)(tau - 1));

    const __hip_bfloat16* h0r = h0bf + (size_t)((tau + 3) & 3) * HSZ;  // h0[tau-1]
    const __hip_bfloat16* h1r = h1bf + (size_t)(tau & 1) * HSZ;        // h1[tau-2]
    __hip_bfloat16*       h1w = h1bf + (size_t)((tau + 1) & 1) * HSZ;  // h1[tau-1]

    f4 zx[3], zh[3];

    bf8v AR[4][4];
    #pragma unroll
    for (int rt = 0; rt < 4; ++rt)
      #pragma unroll
      for (int kt = 0; kt < 4; ++kt)
        AR[rt][kt] = ld16_cross(h0r + (size_t)(16*rt + l15)*HDIM + (4*w + kt)*32 + 8*lg);
    vm_drain();

    f4 AC[3][4];
    #pragma unroll
    for (int g = 0; g < 3; ++g)
      #pragma unroll
      for (int rt = 0; rt < 4; ++rt) AC[g][rt] = f4{0.f,0.f,0.f,0.f};
    #pragma unroll
    for (int kt = 0; kt < 4; ++kt)
      #pragma unroll
      for (int g = 0; g < 3; ++g)
        #pragma unroll
        for (int rt = 0; rt < 4; ++rt){
          AC[g][rt] = mf(AR[rt][kt], BW[g][kt][0], AC[g][rt]);
          AC[g][rt] = mf(AR[rt][kt], BW[g][kt][1], AC[g][rt]);
        }
    #pragma unroll
    for (int g = 0; g < 3; ++g)
      #pragma unroll
      for (int rt = 0; rt < 4; ++rt)
        red[((w*3 + g)*4 + rt)*64 + lane] = AC[g][rt];

    // issue h1 loads (overlap with LDS reduce), reusing AR
    #pragma unroll
    for (int rt = 0; rt < 4; ++rt)
      #pragma unroll
      for (int kt = 0; kt < 4; ++kt)
        AR[rt][kt] = ld16_cross(h1r + (size_t)(16*rt + l15)*HDIM + (4*w + kt)*32 + 8*lg);

    __syncthreads();
    #pragma unroll
    for (int g = 0; g < 3; ++g){
      f4 a = red[((0*3 + g)*4 + w)*64 + lane];
      a += red[((1*3 + g)*4 + w)*64 + lane];
      a += red[((2*3 + g)*4 + w)*64 + lane];
      a += red[((3*3 + g)*4 + w)*64 + lane];
      zx[g] = a;
    }
    __syncthreads();   // all reads of red done before overwrite

    vm_drain();
    #pragma unroll
    for (int g = 0; g < 3; ++g)
      #pragma unroll
      for (int rt = 0; rt < 4; ++rt) AC[g][rt] = f4{0.f,0.f,0.f,0.f};
    #pragma unroll
    for (int kt = 0; kt < 4; ++kt)
      #pragma unroll
      for (int g = 0; g < 3; ++g)
        #pragma unroll
        for (int rt = 0; rt < 4; ++rt){
          AC[g][rt] = mf(AR[rt][kt], BW[3+g][kt][0], AC[g][rt]);
          AC[g][rt] = mf(AR[rt][kt], BW[3+g][kt][1], AC[g][rt]);
        }
    #pragma unroll
    for (int g = 0; g < 3; ++g)
      #pragma unroll
      for (int rt = 0; rt < 4; ++rt)
        red[((w*3 + g)*4 + rt)*64 + lane] = AC[g][rt];
    __syncthreads();
    #pragma unroll
    for (int g = 0; g < 3; ++g){
      f4 a = red[((0*3 + g)*4 + w)*64 + lane];
      a += red[((1*3 + g)*4 + w)*64 + lane];
      a += red[((2*3 + g)*4 + w)*64 + lane];
      a += red[((3*3 + g)*4 + w)*64 + lane];
      zh[g] = a;
    }

    // stat partials -> epoch slots
    #pragma unroll
    for (int r = 0; r < 4; ++r){
      float s1 = zx[0][r] + zx[1][r] + zx[2][r];
      float q1 = zx[0][r]*zx[0][r] + zx[1][r]*zx[1][r] + zx[2][r]*zx[2][r];
      float s2 = zh[0][r] + zh[1][r] + zh[2][r];
      float q2 = zh[0][r]*zh[0][r] + zh[1][r]*zh[1][r] + zh[2][r]*zh[2][r];
      #pragma unroll
      for (int m = 1; m < 16; m <<= 1){
        s1 += __shfl_xor(s1, m); q1 += __shfl_xor(q1, m);
        s2 += __shfl_xor(s2, m); q2 += __shfl_xor(q2, m);
      }
      if (l15 == 0){
        int row = 16*w + 4*lg + r;
        st16f_cross(stB1 + ((size_t)row*32 + s)*4, f4{s1, q1, ef, 0.f});
        st16f_cross(stB2 + ((size_t)row*32 + s)*4, f4{s2, q2, ef, 0.f});
      }
    }

    // batched epoch poll (16 loads, one drain) + reduce
    {
      int row = tid >> 2, q = tid & 3;
      const float* b1 = stB1 + ((size_t)row*32 + q*8)*4;
      const float* b2 = stB2 + ((size_t)row*32 + q*8)*4;
      f4 v1[8], v2[8];
      for (;;){
        #pragma unroll
        for (int i = 0; i < 8; ++i){ v1[i] = ld16f_cross(b1 + i*4); v2[i] = ld16f_cross(b2 + i*4); }
        vm_drain();
        bool ok = true;
        #pragma unroll
        for (int i = 0; i < 8; ++i) ok = ok && (v1[i][2] >= ef) && (v2[i][2] >= ef);
        if (__all((int)ok)) break;
        __builtin_amdgcn_s_sleep(1);
      }
      float s1 = 0.f, q1 = 0.f, s2 = 0.f, q2 = 0.f;
      #pragma unroll
      for (int i = 0; i < 8; ++i){
        s1 += v1[i][0]; q1 += v1[i][1];
        s2 += v2[i][0]; q2 += v2[i][1];
      }
      s1 += __shfl_xor(s1,1); q1 += __shfl_xor(q1,1);
      s1 += __shfl_xor(s1,2); q1 += __shfl_xor(q1,2);
      s2 += __shfl_xor(s2,1); q2 += __shfl_xor(q2,1);
      s2 += __shfl_xor(s2,2); q2 += __shfl_xor(q2,2);
      if (q == 0){
        float m1 = s1*(1.0f/1536.0f);
        float vv1 = fmaxf(q1*(1.0f/1536.0f) - m1*m1, 0.0f);
        BC1[row] = f2{m1, rsqrtf(vv1 + EPSLN)};
        float m2 = s2*(1.0f/1536.0f);
        float vv2 = fmaxf(q2*(1.0f/1536.0f) - m2*m2, 0.0f);
        BC2[row] = f2{m2, rsqrtf(vv2 + EPSLN)};
      }
    }
    __syncthreads();

    // combine + publish h1[tau-1] + output
    const int t1 = tau - 1;
    #pragma unroll
    for (int r = 0; r < 4; ++r){
      int row = 16*w + 4*lg + r;
      f2 m1 = BC1[row], m2 = BC2[row];
      float gxr = (zx[0][r] - m1[0])*m1[1]*PXg[0] + PXb[0];
      float gxi = (zx[1][r] - m1[0])*m1[1]*PXg[1] + PXb[1];
      float gxn = (zx[2][r] - m1[0])*m1[1]*PXg[2] + PXb[2];
      float ghr = (zh[0][r] - m2[0])*m2[1]*PHg[0] + PHb[0];
      float ghi = (zh[1][r] - m2[0])*m2[1]*PHg[1] + PHb[1];
      float ghn = (zh[2][r] - m2[0])*m2[1]*PHg[2] + PHb[2];
      float rg = sigf(gxr + ghr);
      float ig = sigf(gxi + ghi);
      float nn = tanhfast(gxn + rg*ghn);
      float hn = nn + ig*(hp[r] - nn);
      hp[r] = hn;
      int j = 16*s + l15;
      __hip_bfloat16 hb = __float2bfloat16(hn);
      st2_cross(h1w + (size_t)row*HDIM + j,
                (unsigned int)*reinterpret_cast<unsigned short*>(&hb));
      out[(size_t)row*(HDIM*T_STEPS) + (size_t)j*T_STEPS + t1] = hn;
    }

    vm_drain();
    __syncthreads();                 // all threads' h1 stores drained
    if (tid == 0) pubflag(flags, 32 + s, (unsigned)tau);
  }
}

// ---- K3: persistent recurrent kernel, 64 blocks x 256 threads ----
__global__ __launch_bounds__(256,1) void k_rnn(
    const float* __restrict__ gx0g, const float* __restrict__ gx0b,
    const float* __restrict__ gh0g, const float* __restrict__ gh0b,
    const float* __restrict__ gx1g, const float* __restrict__ gx1b,
    const float* __restrict__ gh1g, const float* __restrict__ gh1b,
    unsigned char* __restrict__ ws, float* __restrict__ out)
{
  __shared__ f4 red[4*3*4*64];   // 48 KiB
  __shared__ f2 BCa[64];
  __shared__ f2 BCb[64];

  const int bi = blockIdx.x;
  if (bi < 32)
    runA(bi, ws, red, BCa, gx0g, gx0b, gh0g, gh0b);
  else
    runB(bi - 32, ws, red, BCa, BCb, gx1g, gx1b, gh1g, gh1b, out);
}

// ---------------------------------------------------------------------------
extern "C" void kernel_launch(void* const* d_in, const int* in_sizes, int n_in,
                              void* d_out, int out_size, void* d_ws, size_t ws_size,
                              hipStream_t stream) {
  const float* xs  = (const float*)d_in[0];
  const float* Wx0 = (const float*)d_in[1];
  const float* Wh0 = (const float*)d_in[2];
  const float* gx0g = (const float*)d_in[3];
  const float* gx0b = (const float*)d_in[4];
  const float* gh0g = (const float*)d_in[5];
  const float* gh0b = (const float*)d_in[6];
  const float* Wx1 = (const float*)d_in[7];
  const float* Wh1 = (const float*)d_in[8];
  const float* gx1g = (const float*)d_in[9];
  const float* gx1b = (const float*)d_in[10];
  const float* gh1g = (const float*)d_in[11];
  const float* gh1b = (const float*)d_in[12];

  unsigned char* ws = (unsigned char*)d_ws;
  float* out = (float*)d_out;
  (void)in_sizes; (void)n_in; (void)out_size; (void)ws_size;

  // zero flags + stat slots + h buffers + statsX (head region)
  k_zero<<<256, 256, 0, stream>>>((unsigned int*)ws, (int)(OFF_WH0HI/4));

  // weight hi/lo conversion
  k_conv<<<512, 256, 0, stream>>>(Wh0, (__hip_bfloat16*)(ws+OFF_WH0HI), (__hip_bfloat16*)(ws+OFF_WH0LO), THREE_H*HDIM);
  k_conv<<<512, 256, 0, stream>>>(Wx1, (__hip_bfloat16*)(ws+OFF_WX1HI), (__hip_bfloat16*)(ws+OFF_WX1LO), THREE_H*HDIM);
  k_conv<<<512, 256, 0, stream>>>(Wh1, (__hip_bfloat16*)(ws+OFF_WH1HI), (__hip_bfloat16*)(ws+OFF_WH1LO), THREE_H*HDIM);
  k_conv<<<512, 256, 0, stream>>>(Wx0, (__hip_bfloat16*)(ws+OFF_WX0HI), (__hip_bfloat16*)(ws+OFF_WX0LO), THREE_H*CINDIM);

  // xs transpose -> xsT bf16
  k_tr<<<4096, 256, 0, stream>>>(xs, (__hip_bfloat16*)(ws+OFF_XST));

  // x-path GEMM for all timesteps
  k_xgemm<<<16384, 256, 0, stream>>>(ws);
  k_statsx<<<256, 256, 0, stream>>>((float*)(ws+OFF_STATSX));

  // barrier-free pipelined recurrence
  k_rnn<<<NBLK, 256, 0, stream>>>(gx0g, gx0b, gh0g, gh0b, gx1g, gx1b, gh1g, gh1b, ws, out);
}

// Round 11
// 12866.418 us; speedup vs baseline: 1.3032x; 1.2913x over previous
//
#include <hip/hip_runtime.h>
#include <hip/hip_bf16.h>
#include <cstdint>
#include <cstddef>

// ---------------------------------------------------------------------------
// StackedLayerNormGRU  (B=64, C_IN=256, H=512, T=1024)
//
// Round 11: revert to R6 verbatim — the measured optimum (12.4 ms k_rnn).
//  - 64 blocks: 32 "A" (layer-0, Wh0 strip in regs, ~250 VGPR) +
//               32 "B" (layer-1, Wx1+Wh1 strips in regs, sequential GEMMs
//               reusing one AR set).
//  - 2 distributed-flag barriers/step (64 flags x 128B, all-wave polling),
//    sc0 sc1 for all cross-block data, stat partials + tree reduce.
//  - R7 (packed flags/wave0 poll), R8 (epoch slots), R9 (XCD-local),
//    R10 (barrier-free pipeline) all regressed or hung; this protocol is
//    the empirical floor for the 2-sync-per-step dependency graph.
// ---------------------------------------------------------------------------

#define NBATCH 64
#define HDIM   512
#define THREE_H 1536
#define CINDIM 256
#define T_STEPS 1024
#define EPSLN 1e-5f
#define NBLK 64   // 32 A-blocks (L0) + 32 B-blocks (L1)

typedef __bf16 bf8v __attribute__((ext_vector_type(8)));
typedef float f4 __attribute__((ext_vector_type(4)));
typedef float f2 __attribute__((ext_vector_type(2)));
typedef unsigned int u32x4 __attribute__((ext_vector_type(4)));

// ---- workspace layout (bytes) ----
static constexpr size_t OFF_BAR    = 0;          // 64 flags x 128B = 8192
static constexpr size_t OFF_ST0P   = 8192;       // [64][32][2] f32 = 16384
static constexpr size_t OFF_ST1P   = 24576;      // [64][32][2] f32
static constexpr size_t OFF_ST2P   = 40960;      // [64][32][2] f32
static constexpr size_t OFF_H0BF   = 57344;      // 64*512 bf16 = 65536
static constexpr size_t OFF_H1BF   = 122880;     // 65536
static constexpr size_t OFF_STATSX = 188416;     // [1024][64][2] f32 = 524288
static constexpr size_t OFF_WH0HI  = 712704;     // 1536*512 bf16 = 1572864 each
static constexpr size_t OFF_WH0LO  = OFF_WH0HI + 1572864;
static constexpr size_t OFF_WX1HI  = OFF_WH0LO + 1572864;
static constexpr size_t OFF_WX1LO  = OFF_WX1HI + 1572864;
static constexpr size_t OFF_WH1HI  = OFF_WX1LO + 1572864;
static constexpr size_t OFF_WH1LO  = OFF_WH1HI + 1572864;
static constexpr size_t OFF_WX0HI  = OFF_WH1LO + 1572864;   // 1536*256 bf16
static constexpr size_t OFF_WX0LO  = OFF_WX0HI + 786432;
static constexpr size_t OFF_XST    = OFF_WX0LO + 786432;    // 33554432
static constexpr size_t OFF_GX0    = OFF_XST + 33554432;    // 201326592

__device__ __forceinline__ f4 mf(bf8v a, bf8v b, f4 c){
  return __builtin_amdgcn_mfma_f32_16x16x32_bf16(a, b, c, 0, 0, 0);
}
__device__ __forceinline__ float sigf(float x){ return 1.0f/(1.0f + __expf(-x)); }
__device__ __forceinline__ float tanhfast(float x){ return 1.0f - 2.0f/(__expf(2.0f*x) + 1.0f); }

// ---- device-coherent (MALL) access helpers ----
__device__ __forceinline__ bf8v ld16_cross(const void* p){
  u32x4 t;
  asm volatile("global_load_dwordx4 %0, %1, off sc0 sc1" : "=v"(t) : "v"(p));
  return __builtin_bit_cast(bf8v, t);
}
__device__ __forceinline__ f4 ld16f_cross(const float* p){
  f4 v;
  asm volatile("global_load_dwordx4 %0, %1, off sc0 sc1" : "=v"(v) : "v"(p));
  return v;
}
__device__ __forceinline__ void st2_cross(__hip_bfloat16* p, unsigned int u){
  asm volatile("global_store_short %0, %1, off sc0 sc1" :: "v"(p), "v"(u));
}
__device__ __forceinline__ void st8f_cross(float* p, f2 v){
  asm volatile("global_store_dwordx2 %0, %1, off sc0 sc1" :: "v"(p), "v"(v));
}
__device__ __forceinline__ void vm_drain(){
  asm volatile("s_waitcnt vmcnt(0)" ::: "memory");
  __builtin_amdgcn_sched_barrier(0);
}

// ---- distributed flag barrier: 64 flags, 128B apart, epoch-numbered ----
__device__ __forceinline__ void gbar(unsigned int* flags, unsigned int target){
  asm volatile("s_waitcnt vmcnt(0) lgkmcnt(0)" ::: "memory");
  __syncthreads();
  if (threadIdx.x == 0){
    unsigned int* myf = flags + (size_t)blockIdx.x * 32;
    asm volatile("global_store_dword %0, %1, off sc0 sc1" :: "v"(myf), "v"(target) : "memory");
  }
  const int lane = threadIdx.x & 63;
  const unsigned int* pf = flags + (size_t)lane * 32;
  for (;;){
    unsigned int v;
    asm volatile("global_load_dword %0, %1, off sc0 sc1\n\ts_waitcnt vmcnt(0)"
                 : "=v"(v) : "v"(pf) : "memory");
    if (__all((int)(v >= target))) break;
    __builtin_amdgcn_s_sleep(1);
  }
}

// ---- K0: zero head of workspace ----
__global__ void k_zero(unsigned int* p, int nwords){
  for (int i = blockIdx.x*blockDim.x + threadIdx.x; i < nwords; i += gridDim.x*blockDim.x)
    p[i] = 0u;
}

// ---- K1: fp32 weight -> bf16 hi/lo split ----
__global__ void k_conv(const float* __restrict__ src, __hip_bfloat16* __restrict__ hi,
                       __hip_bfloat16* __restrict__ lo, int n){
  for (int i = blockIdx.x*blockDim.x + threadIdx.x; i < n; i += gridDim.x*blockDim.x){
    float w = src[i];
    __hip_bfloat16 h = __float2bfloat16(w);
    hi[i] = h;
    lo[i] = __float2bfloat16(w - __bfloat162float(h));
  }
}

// ---- K1b: xs [B][C][T] f32 -> xsT [T][B][C] bf16 ----
__global__ void k_tr(const float* __restrict__ xs, __hip_bfloat16* __restrict__ xsT){
  const int total = NBATCH * CINDIM * (T_STEPS/4);
  for (int idx = blockIdx.x*blockDim.x + threadIdx.x; idx < total; idx += gridDim.x*blockDim.x){
    int b  = idx >> 16;
    int c  = (idx >> 8) & 255;
    int t4 = idx & 255;
    const float4 v = *(const float4*)(xs + ((size_t)b*CINDIM + c)*T_STEPS + t4*4);
    float vv[4] = {v.x, v.y, v.z, v.w};
    #pragma unroll
    for (int i = 0; i < 4; ++i)
      xsT[(size_t)(4*t4 + i)*(NBATCH*CINDIM) + b*CINDIM + c] = __float2bfloat16(vv[i]);
  }
}

// ---- K2: gate_x0 raw GEMM + stat atomics (proven code) ----
__global__ __launch_bounds__(256,1) void k_xgemm(unsigned char* __restrict__ ws){
  const int tid = threadIdx.x;
  const int bx = blockIdx.x;
  const int t = bx >> 4, s = bx & 15;
  const int lane = tid & 63, w = tid >> 6, l15 = lane & 15, lg = lane >> 4;

  const __hip_bfloat16* X  = (const __hip_bfloat16*)(ws + OFF_XST) + (size_t)t*(NBATCH*CINDIM);
  const __hip_bfloat16* WH = (const __hip_bfloat16*)(ws + OFF_WX0HI);
  const __hip_bfloat16* WL = (const __hip_bfloat16*)(ws + OFF_WX0LO);
  float* statsX = (float*)(ws + OFF_STATSX);
  __hip_bfloat16* GX0 = (__hip_bfloat16*)(ws + OFF_GX0) + (size_t)t*(NBATCH*THREE_H);

  __shared__ __hip_bfloat16 SB[2][2][96][72];

  f4 acc[6];
  #pragma unroll
  for (int i = 0; i < 6; ++i) acc[i] = f4{0.f,0.f,0.f,0.f};

  bf8v A0[8];
  #pragma unroll
  for (int kk = 0; kk < 8; ++kk)
    A0[kk] = *(const bf8v*)(X + (16*w + l15)*CINDIM + kk*32 + 8*lg);

  bf8v pre[6];
  #pragma unroll
  for (int rep = 0; rep < 6; ++rep){
    int idx = tid + rep*256; int half = idx >= 768 ? 1 : 0; int i2 = idx - half*768;
    int rr = i2 >> 3, ko = (i2 & 7)*8;
    int j = 32*s + (rr & 31) + 512*(rr >> 5);
    const __hip_bfloat16* sp = (half ? WL : WH) + (size_t)j*CINDIM;
    pre[rep] = *(const bf8v*)(sp + ko);
  }
  #pragma unroll
  for (int chk = 0; chk < 4; ++chk){
    #pragma unroll
    for (int rep = 0; rep < 6; ++rep){
      int idx = tid + rep*256; int half = idx >= 768 ? 1 : 0; int i2 = idx - half*768;
      int rr = i2 >> 3, ko = (i2 & 7)*8;
      *(bf8v*)&SB[chk & 1][half][rr][ko] = pre[rep];
    }
    __syncthreads();
    if (chk < 3){
      #pragma unroll
      for (int rep = 0; rep < 6; ++rep){
        int idx = tid + rep*256; int half = idx >= 768 ? 1 : 0; int i2 = idx - half*768;
        int rr = i2 >> 3, ko = (i2 & 7)*8;
        int j = 32*s + (rr & 31) + 512*(rr >> 5);
        const __hip_bfloat16* sp = (half ? WL : WH) + (size_t)j*CINDIM;
        pre[rep] = *(const bf8v*)(sp + (chk+1)*64 + ko);
      }
    }
    #pragma unroll
    for (int sub = 0; sub < 2; ++sub){
      int kk = 2*chk + sub; int ko = 32*sub + 8*lg;
      bf8v a = A0[kk];
      #pragma unroll
      for (int nf = 0; nf < 6; ++nf){
        bf8v bh = *(const bf8v*)&SB[chk & 1][0][16*nf + l15][ko];
        bf8v bl = *(const bf8v*)&SB[chk & 1][1][16*nf + l15][ko];
        acc[nf] = mf(a, bh, acc[nf]);
        acc[nf] = mf(a, bl, acc[nf]);
      }
    }
  }

  #pragma unroll
  for (int r = 0; r < 4; ++r){
    int row = 16*w + 4*lg + r;
    float sm = 0.f, sq = 0.f;
    #pragma unroll
    for (int nf = 0; nf < 6; ++nf){
      float v = acc[nf][r];
      sm += v; sq += v*v;
      int tc = 16*nf + l15;
      int j = 32*s + (tc & 31) + 512*(tc >> 5);
      GX0[(size_t)row*THREE_H + j] = __float2bfloat16(v);
    }
    #pragma unroll
    for (int m = 1; m < 16; m <<= 1){ sm += __shfl_xor(sm, m); sq += __shfl_xor(sq, m); }
    if (l15 == 0){
      atomicAdd(&statsX[((size_t)t*64 + row)*2 + 0], sm);
      atomicAdd(&statsX[((size_t)t*64 + row)*2 + 1], sq);
    }
  }
}

// ---- K2b: finalize x stats ----
__global__ void k_statsx(float* __restrict__ sx){
  int i = blockIdx.x*blockDim.x + threadIdx.x;
  if (i < T_STEPS*NBATCH){
    float s = sx[2*i], q = sx[2*i+1];
    float m = s * (1.0f/1536.0f);
    float v = fmaxf(q * (1.0f/1536.0f) - m*m, 0.0f);
    sx[2*i] = m;
    sx[2*i+1] = rsqrtf(v + EPSLN);
  }
}

// ===========================================================================
// K3 worker paths.
// ===========================================================================

// ---- A-path: layer-0 recurrence, Wh0 strip in registers (~250 VGPR) ----
__device__ __forceinline__ void runA(
    int s, unsigned char* ws, f4* red, f2* BC0,
    const float* gxg, const float* gxb, const float* ghg, const float* ghb)
{
  const int tid = threadIdx.x, lane = tid & 63, w = tid >> 6;
  const int l15 = lane & 15, lg = (lane >> 4) & 3;

  unsigned int* flags = (unsigned int*)(ws + OFF_BAR);
  float* st0P = (float*)(ws + OFF_ST0P);
  __hip_bfloat16* h0bf = (__hip_bfloat16*)(ws + OFF_H0BF);
  const float* statsX = (const float*)(ws + OFF_STATSX);
  const __hip_bfloat16* GX0 = (const __hip_bfloat16*)(ws + OFF_GX0);

  bf8v BW[3][4][2];
  {
    const __hip_bfloat16* hi = (const __hip_bfloat16*)(ws + OFF_WH0HI);
    const __hip_bfloat16* lo = (const __hip_bfloat16*)(ws + OFF_WH0LO);
    #pragma unroll
    for (int g = 0; g < 3; ++g){
      const size_t j = (size_t)(16*s + l15 + 512*g);
      #pragma unroll
      for (int kt = 0; kt < 4; ++kt){
        const size_t ko = (size_t)((4*w + kt)*32 + 8*lg);
        BW[g][kt][0] = *(const bf8v*)(hi + j*HDIM + ko);
        BW[g][kt][1] = *(const bf8v*)(lo + j*HDIM + ko);
      }
    }
  }
  float PXg[3], PXb[3], PHg[3], PHb[3];
  #pragma unroll
  for (int g = 0; g < 3; ++g){
    int j = 16*s + l15 + 512*g;
    PXg[g] = gxg[j]; PXb[g] = gxb[j]; PHg[g] = ghg[j]; PHb[g] = ghb[j];
  }

  float hp[4] = {0.f,0.f,0.f,0.f};
  unsigned int bc = 0;

  for (int tau = 0; tau <= T_STEPS; ++tau){
    const bool act = (tau < T_STEPS);
    f4 zx[3];
    float gxraw[3][4], mxv[4], rsxv[4];

    if (act){
      bf8v AR[4][4];
      #pragma unroll
      for (int rt = 0; rt < 4; ++rt)
        #pragma unroll
        for (int kt = 0; kt < 4; ++kt)
          AR[rt][kt] = ld16_cross(h0bf + (size_t)(16*rt + l15)*HDIM + (4*w + kt)*32 + 8*lg);
      vm_drain();

      f4 AC[3][4];
      #pragma unroll
      for (int g = 0; g < 3; ++g)
        #pragma unroll
        for (int rt = 0; rt < 4; ++rt) AC[g][rt] = f4{0.f,0.f,0.f,0.f};
      #pragma unroll
      for (int kt = 0; kt < 4; ++kt)
        #pragma unroll
        for (int g = 0; g < 3; ++g)
          #pragma unroll
          for (int rt = 0; rt < 4; ++rt){
            AC[g][rt] = mf(AR[rt][kt], BW[g][kt][0], AC[g][rt]);
            AC[g][rt] = mf(AR[rt][kt], BW[g][kt][1], AC[g][rt]);
          }

      #pragma unroll
      for (int r = 0; r < 4; ++r){
        int row = 16*w + 4*lg + r;
        mxv[r]  = statsX[((size_t)tau*64 + row)*2 + 0];
        rsxv[r] = statsX[((size_t)tau*64 + row)*2 + 1];
        #pragma unroll
        for (int g = 0; g < 3; ++g)
          gxraw[g][r] = __bfloat162float(
            GX0[(size_t)tau*(NBATCH*THREE_H) + (size_t)row*THREE_H + (16*s + l15 + 512*g)]);
      }

      #pragma unroll
      for (int g = 0; g < 3; ++g)
        #pragma unroll
        for (int rt = 0; rt < 4; ++rt)
          red[((w*3 + g)*4 + rt)*64 + lane] = AC[g][rt];
      __syncthreads();
      #pragma unroll
      for (int g = 0; g < 3; ++g){
        f4 a = red[((0*3 + g)*4 + w)*64 + lane];
        a += red[((1*3 + g)*4 + w)*64 + lane];
        a += red[((2*3 + g)*4 + w)*64 + lane];
        a += red[((3*3 + g)*4 + w)*64 + lane];
        zx[g] = a;
      }

      #pragma unroll
      for (int r = 0; r < 4; ++r){
        float s1 = zx[0][r] + zx[1][r] + zx[2][r];
        float q1 = zx[0][r]*zx[0][r] + zx[1][r]*zx[1][r] + zx[2][r]*zx[2][r];
        #pragma unroll
        for (int m = 1; m < 16; m <<= 1){ s1 += __shfl_xor(s1, m); q1 += __shfl_xor(q1, m); }
        if (l15 == 0){
          int row = 16*w + 4*lg + r;
          st8f_cross(st0P + ((size_t)row*32 + s)*2, f2{s1, q1});
        }
      }
    }

    gbar(flags, ++bc);   // B1

    if (act){
      {
        int row = tid >> 2, q = tid & 3;
        const float* bp = st0P + (size_t)row*64 + q*16;
        f4 v0 = ld16f_cross(bp),   v1 = ld16f_cross(bp+4);
        f4 v2 = ld16f_cross(bp+8), v3 = ld16f_cross(bp+12);
        vm_drain();
        float sm = v0[0]+v0[2]+v1[0]+v1[2]+v2[0]+v2[2]+v3[0]+v3[2];
        float sq = v0[1]+v0[3]+v1[1]+v1[3]+v2[1]+v2[3]+v3[1]+v3[3];
        sm += __shfl_xor(sm,1); sq += __shfl_xor(sq,1);
        sm += __shfl_xor(sm,2); sq += __shfl_xor(sq,2);
        if (q == 0){
          float m = sm*(1.0f/1536.0f);
          float vv = fmaxf(sq*(1.0f/1536.0f) - m*m, 0.0f);
          BC0[row] = f2{m, rsqrtf(vv + EPSLN)};
        }
      }
      __syncthreads();
      #pragma unroll
      for (int r = 0; r < 4; ++r){
        int row = 16*w + 4*lg + r;
        f2 mr = BC0[row];
        float m = mr[0], rs = mr[1];
        float ghr = (zx[0][r]-m)*rs*PHg[0] + PHb[0];
        float ghi = (zx[1][r]-m)*rs*PHg[1] + PHb[1];
        float ghn = (zx[2][r]-m)*rs*PHg[2] + PHb[2];
        float gxr = (gxraw[0][r] - mxv[r])*rsxv[r]*PXg[0] + PXb[0];
        float gxi = (gxraw[1][r] - mxv[r])*rsxv[r]*PXg[1] + PXb[1];
        float gxn = (gxraw[2][r] - mxv[r])*rsxv[r]*PXg[2] + PXb[2];
        float rg = sigf(gxr + ghr);
        float ig = sigf(gxi + ghi);
        float nn = tanhfast(gxn + rg*ghn);
        float hn = nn + ig*(hp[r] - nn);
        hp[r] = hn;
        __hip_bfloat16 hb = __float2bfloat16(hn);
        st2_cross(h0bf + (size_t)row*HDIM + 16*s + l15,
                  (unsigned int)*reinterpret_cast<unsigned short*>(&hb));
      }
    }

    gbar(flags, ++bc);   // B2
  }
}

// ---- B-path: layer-1, Wx1+Wh1 strips in regs, sequential GEMMs ----
__device__ __forceinline__ void runB(
    int s, unsigned char* ws, f4* red, f2* BC1, f2* BC2,
    const float* gxg, const float* gxb, const float* ghg, const float* ghb,
    float* out)
{
  const int tid = threadIdx.x, lane = tid & 63, w = tid >> 6;
  const int l15 = lane & 15, lg = (lane >> 4) & 3;

  unsigned int* flags = (unsigned int*)(ws + OFF_BAR);
  float* st1P = (float*)(ws + OFF_ST1P);
  float* st2P = (float*)(ws + OFF_ST2P);
  __hip_bfloat16* h0bf = (__hip_bfloat16*)(ws + OFF_H0BF);
  __hip_bfloat16* h1bf = (__hip_bfloat16*)(ws + OFF_H1BF);

  bf8v BW[6][4][2];
  {
    const __hip_bfloat16* hix = (const __hip_bfloat16*)(ws + OFF_WX1HI);
    const __hip_bfloat16* lox = (const __hip_bfloat16*)(ws + OFF_WX1LO);
    const __hip_bfloat16* hih = (const __hip_bfloat16*)(ws + OFF_WH1HI);
    const __hip_bfloat16* loh = (const __hip_bfloat16*)(ws + OFF_WH1LO);
    #pragma unroll
    for (int g = 0; g < 3; ++g){
      const size_t j = (size_t)(16*s + l15 + 512*g);
      #pragma unroll
      for (int kt = 0; kt < 4; ++kt){
        const size_t ko = (size_t)((4*w + kt)*32 + 8*lg);
        BW[g][kt][0]   = *(const bf8v*)(hix + j*HDIM + ko);
        BW[g][kt][1]   = *(const bf8v*)(lox + j*HDIM + ko);
        BW[3+g][kt][0] = *(const bf8v*)(hih + j*HDIM + ko);
        BW[3+g][kt][1] = *(const bf8v*)(loh + j*HDIM + ko);
      }
    }
  }
  float PXg[3], PXb[3], PHg[3], PHb[3];
  #pragma unroll
  for (int g = 0; g < 3; ++g){
    int j = 16*s + l15 + 512*g;
    PXg[g] = gxg[j]; PXb[g] = gxb[j]; PHg[g] = ghg[j]; PHb[g] = ghb[j];
  }

  float hp[4] = {0.f,0.f,0.f,0.f};
  unsigned int bc = 0;

  for (int tau = 0; tau <= T_STEPS; ++tau){
    const bool act = (tau >= 1);
    f4 zx[3], zh[3];

    if (act){
      bf8v AR[4][4];
      #pragma unroll
      for (int rt = 0; rt < 4; ++rt)
        #pragma unroll
        for (int kt = 0; kt < 4; ++kt)
          AR[rt][kt] = ld16_cross(h0bf + (size_t)(16*rt + l15)*HDIM + (4*w + kt)*32 + 8*lg);
      vm_drain();

      f4 AC[3][4];
      #pragma unroll
      for (int g = 0; g < 3; ++g)
        #pragma unroll
        for (int rt = 0; rt < 4; ++rt) AC[g][rt] = f4{0.f,0.f,0.f,0.f};
      #pragma unroll
      for (int kt = 0; kt < 4; ++kt)
        #pragma unroll
        for (int g = 0; g < 3; ++g)
          #pragma unroll
          for (int rt = 0; rt < 4; ++rt){
            AC[g][rt] = mf(AR[rt][kt], BW[g][kt][0], AC[g][rt]);
            AC[g][rt] = mf(AR[rt][kt], BW[g][kt][1], AC[g][rt]);
          }
      #pragma unroll
      for (int g = 0; g < 3; ++g)
        #pragma unroll
        for (int rt = 0; rt < 4; ++rt)
          red[((w*3 + g)*4 + rt)*64 + lane] = AC[g][rt];

      #pragma unroll
      for (int rt = 0; rt < 4; ++rt)
        #pragma unroll
        for (int kt = 0; kt < 4; ++kt)
          AR[rt][kt] = ld16_cross(h1bf + (size_t)(16*rt + l15)*HDIM + (4*w + kt)*32 + 8*lg);

      __syncthreads();
      #pragma unroll
      for (int g = 0; g < 3; ++g){
        f4 a = red[((0*3 + g)*4 + w)*64 + lane];
        a += red[((1*3 + g)*4 + w)*64 + lane];
        a += red[((2*3 + g)*4 + w)*64 + lane];
        a += red[((3*3 + g)*4 + w)*64 + lane];
        zx[g] = a;
      }
      __syncthreads();

      vm_drain();
      #pragma unroll
      for (int g = 0; g < 3; ++g)
        #pragma unroll
        for (int rt = 0; rt < 4; ++rt) AC[g][rt] = f4{0.f,0.f,0.f,0.f};
      #pragma unroll
      for (int kt = 0; kt < 4; ++kt)
        #pragma unroll
        for (int g = 0; g < 3; ++g)
          #pragma unroll
          for (int rt = 0; rt < 4; ++rt){
            AC[g][rt] = mf(AR[rt][kt], BW[3+g][kt][0], AC[g][rt]);
            AC[g][rt] = mf(AR[rt][kt], BW[3+g][kt][1], AC[g][rt]);
          }
      #pragma unroll
      for (int g = 0; g < 3; ++g)
        #pragma unroll
        for (int rt = 0; rt < 4; ++rt)
          red[((w*3 + g)*4 + rt)*64 + lane] = AC[g][rt];
      __syncthreads();
      #pragma unroll
      for (int g = 0; g < 3; ++g){
        f4 a = red[((0*3 + g)*4 + w)*64 + lane];
        a += red[((1*3 + g)*4 + w)*64 + lane];
        a += red[((2*3 + g)*4 + w)*64 + lane];
        a += red[((3*3 + g)*4 + w)*64 + lane];
        zh[g] = a;
      }

      #pragma unroll
      for (int r = 0; r < 4; ++r){
        float s1 = zx[0][r] + zx[1][r] + zx[2][r];
        float q1 = zx[0][r]*zx[0][r] + zx[1][r]*zx[1][r] + zx[2][r]*zx[2][r];
        float s2 = zh[0][r] + zh[1][r] + zh[2][r];
        float q2 = zh[0][r]*zh[0][r] + zh[1][r]*zh[1][r] + zh[2][r]*zh[2][r];
        #pragma unroll
        for (int m = 1; m < 16; m <<= 1){
          s1 += __shfl_xor(s1, m); q1 += __shfl_xor(q1, m);
          s2 += __shfl_xor(s2, m); q2 += __shfl_xor(q2, m);
        }
        if (l15 == 0){
          int row = 16*w + 4*lg + r;
          st8f_cross(st1P + ((size_t)row*32 + s)*2, f2{s1, q1});
          st8f_cross(st2P + ((size_t)row*32 + s)*2, f2{s2, q2});
        }
      }
    }

    gbar(flags, ++bc);   // B1

    if (act){
      const int t1 = tau - 1;
      {
        int row = tid >> 2, q = tid & 3;
        const float* b1 = st1P + (size_t)row*64 + q*16;
        const float* b2 = st2P + (size_t)row*64 + q*16;
        f4 a0 = ld16f_cross(b1),   a1 = ld16f_cross(b1+4);
        f4 a2 = ld16f_cross(b1+8), a3 = ld16f_cross(b1+12);
        f4 c0 = ld16f_cross(b2),   c1 = ld16f_cross(b2+4);
        f4 c2 = ld16f_cross(b2+8), c3 = ld16f_cross(b2+12);
        vm_drain();
        float s1 = a0[0]+a0[2]+a1[0]+a1[2]+a2[0]+a2[2]+a3[0]+a3[2];
        float q1 = a0[1]+a0[3]+a1[1]+a1[3]+a2[1]+a2[3]+a3[1]+a3[3];
        float s2 = c0[0]+c0[2]+c1[0]+c1[2]+c2[0]+c2[2]+c3[0]+c3[2];
        float q2 = c0[1]+c0[3]+c1[1]+c1[3]+c2[1]+c2[3]+c3[1]+c3[3];
        s1 += __shfl_xor(s1,1); q1 += __shfl_xor(q1,1);
        s1 += __shfl_xor(s1,2); q1 += __shfl_xor(q1,2);
        s2 += __shfl_xor(s2,1); q2 += __shfl_xor(q2,1);
        s2 += __shfl_xor(s2,2); q2 += __shfl_xor(q2,2);
        if (q == 0){
          float m1 = s1*(1.0f/1536.0f);
          float v1 = fmaxf(q1*(1.0f/1536.0f) - m1*m1, 0.0f);
          BC1[row] = f2{m1, rsqrtf(v1 + EPSLN)};
          float m2 = s2*(1.0f/1536.0f);
          float v2 = fmaxf(q2*(1.0f/1536.0f) - m2*m2, 0.0f);
          BC2[row] = f2{m2, rsqrtf(v2 + EPSLN)};
        }
      }
      __syncthreads();
      #pragma unroll
      for (int r = 0; r < 4; ++r){
        int row = 16*w + 4*lg + r;
        f2 m1 = BC1[row], m2 = BC2[row];
        float gxr = (zx[0][r] - m1[0])*m1[1]*PXg[0] + PXb[0];
        float gxi = (zx[1][r] - m1[0])*m1[1]*PXg[1] + PXb[1];
        float gxn = (zx[2][r] - m1[0])*m1[1]*PXg[2] + PXb[2];
        float ghr = (zh[0][r] - m2[0])*m2[1]*PHg[0] + PHb[0];
        float ghi = (zh[1][r] - m2[0])*m2[1]*PHg[1] + PHb[1];
        float ghn = (zh[2][r] - m2[0])*m2[1]*PHg[2] + PHb[2];
        float rg = sigf(gxr + ghr);
        float ig = sigf(gxi + ghi);
        float nn = tanhfast(gxn + rg*ghn);
        float hn = nn + ig*(hp[r] - nn);
        hp[r] = hn;
        int j = 16*s + l15;
        __hip_bfloat16 hb = __float2bfloat16(hn);
        st2_cross(h1bf + (size_t)row*HDIM + j,
                  (unsigned int)*reinterpret_cast<unsigned short*>(&hb));
        out[(size_t)row*(HDIM*T_STEPS) + (size_t)j*T_STEPS + t1] = hn;
      }
    }

    gbar(flags, ++bc);   // B2
  }
}

// ---- K3: persistent recurrent kernel, 64 blocks x 256 threads ----
__global__ __launch_bounds__(256,1) void k_rnn(
    const float* __restrict__ gx0g, const float* __restrict__ gx0b,
    const float* __restrict__ gh0g, const float* __restrict__ gh0b,
    const float* __restrict__ gx1g, const float* __restrict__ gx1b,
    const float* __restrict__ gh1g, const float* __restrict__ gh1b,
    unsigned char* __restrict__ ws, float* __restrict__ out)
{
  __shared__ f4 red[4*3*4*64];   // 48 KiB
  __shared__ f2 BCa[64];
  __shared__ f2 BCb[64];

  const int bi = blockIdx.x;
  if (bi < 32)
    runA(bi, ws, red, BCa, gx0g, gx0b, gh0g, gh0b);
  else
    runB(bi - 32, ws, red, BCa, BCb, gx1g, gx1b, gh1g, gh1b, out);
}

// ---------------------------------------------------------------------------
extern "C" void kernel_launch(void* const* d_in, const int* in_sizes, int n_in,
                              void* d_out, int out_size, void* d_ws, size_t ws_size,
                              hipStream_t stream) {
  const float* xs  = (const float*)d_in[0];
  const float* Wx0 = (const float*)d_in[1];
  const float* Wh0 = (const float*)d_in[2];
  const float* gx0g = (const float*)d_in[3];
  const float* gx0b = (const float*)d_in[4];
  const float* gh0g = (const float*)d_in[5];
  const float* gh0b = (const float*)d_in[6];
  const float* Wx1 = (const float*)d_in[7];
  const float* Wh1 = (const float*)d_in[8];
  const float* gx1g = (const float*)d_in[9];
  const float* gx1b = (const float*)d_in[10];
  const float* gh1g = (const float*)d_in[11];
  const float* gh1b = (const float*)d_in[12];

  unsigned char* ws = (unsigned char*)d_ws;
  float* out = (float*)d_out;
  (void)in_sizes; (void)n_in; (void)out_size; (void)ws_size;

  // zero flags + stat partials + h0/h1 + statsX (head region)
  k_zero<<<256, 256, 0, stream>>>((unsigned int*)ws, (int)(OFF_WH0HI/4));

  // weight hi/lo conversion
  k_conv<<<512, 256, 0, stream>>>(Wh0, (__hip_bfloat16*)(ws+OFF_WH0HI), (__hip_bfloat16*)(ws+OFF_WH0LO), THREE_H*HDIM);
  k_conv<<<512, 256, 0, stream>>>(Wx1, (__hip_bfloat16*)(ws+OFF_WX1HI), (__hip_bfloat16*)(ws+OFF_WX1LO), THREE_H*HDIM);
  k_conv<<<512, 256, 0, stream>>>(Wh1, (__hip_bfloat16*)(ws+OFF_WH1HI), (__hip_bfloat16*)(ws+OFF_WH1LO), THREE_H*HDIM);
  k_conv<<<512, 256, 0, stream>>>(Wx0, (__hip_bfloat16*)(ws+OFF_WX0HI), (__hip_bfloat16*)(ws+OFF_WX0LO), THREE_H*CINDIM);

  // xs transpose -> xsT bf16
  k_tr<<<4096, 256, 0, stream>>>(xs, (__hip_bfloat16*)(ws+OFF_XST));

  // x-path GEMM for all timesteps
  k_xgemm<<<16384, 256, 0, stream>>>(ws);
  k_statsx<<<256, 256, 0, stream>>>((float*)(ws+OFF_STATSX));

  // persistent recurrence
  k_rnn<<<NBLK, 256, 0, stream>>>(gx0g, gx0b, gh0g, gh0b, gx1g, gx1b, gh1g, gh1b, ws, out);
}